// Round 1
// baseline (1200.727 us; speedup 1.0000x reference)
//
#include <hip/hip_runtime.h>
#include <math.h>

#define L_SEQ 8192
#define B_SZ  2
#define CH    256
#define NLEV  4

static __device__ __forceinline__ float sigmoidf_(float x) {
    return 1.0f / (1.0f + expf(-x));
}

// ---------------------------------------------------------------------------
// Tiled GEMM: out[m,n] = sum_k A[m*Kd+k] * W[n*Kd+k] (+ bias[n])
// A: (M, Kd) row-major, W: (N, Kd) row-major (i.e. computes A @ W^T).
// Requires M%64==0, N%64==0, Kd%32==0.
// ---------------------------------------------------------------------------
__global__ __launch_bounds__(256) void gemm_abt(
    const float* __restrict__ A, const float* __restrict__ W,
    float* __restrict__ out, int M, int N, int Kd,
    const float* __restrict__ bias)
{
    __shared__ float As[64][33];
    __shared__ float Ws[64][33];
    const int tid = threadIdx.x;
    const int bm = blockIdx.y * 64;
    const int bn = blockIdx.x * 64;
    const int tx = tid & 15, ty = tid >> 4;
    float acc[4][4] = {};
    for (int k0 = 0; k0 < Kd; k0 += 32) {
        #pragma unroll
        for (int i = tid; i < 64 * 32; i += 256) {
            int r = i >> 5, c = i & 31;
            As[r][c] = A[(size_t)(bm + r) * Kd + (k0 + c)];
        }
        #pragma unroll
        for (int i = tid; i < 64 * 32; i += 256) {
            int r = i >> 5, c = i & 31;
            Ws[r][c] = W[(size_t)(bn + r) * Kd + (k0 + c)];
        }
        __syncthreads();
        #pragma unroll
        for (int kk = 0; kk < 32; ++kk) {
            float a[4], w[4];
            #pragma unroll
            for (int i = 0; i < 4; ++i) a[i] = As[ty * 4 + i][kk];
            #pragma unroll
            for (int j = 0; j < 4; ++j) w[j] = Ws[tx * 4 + j][kk];
            #pragma unroll
            for (int i = 0; i < 4; ++i)
                #pragma unroll
                for (int j = 0; j < 4; ++j)
                    acc[i][j] += a[i] * w[j];
        }
        __syncthreads();
    }
    #pragma unroll
    for (int i = 0; i < 4; ++i) {
        int m = bm + ty * 4 + i;
        #pragma unroll
        for (int j = 0; j < 4; ++j) {
            int n = bn + tx * 4 + j;
            float v = acc[i][j];
            if (bias) v += bias[n];
            out[(size_t)m * N + n] = v;
        }
    }
}

// ---------------------------------------------------------------------------
// Stem: h[m,o] = sum_i x[m-1,i]*sw[o,i,0] + x[m,i]*sw[o,i,1] + sb[o]
// Virtual A: (M, 512), virtual W: (256, 512). M = B*L.
// ---------------------------------------------------------------------------
__global__ __launch_bounds__(256) void stem_gemm(
    const float* __restrict__ x, const float* __restrict__ sw,
    const float* __restrict__ sb, float* __restrict__ out)
{
    __shared__ float As[64][33];
    __shared__ float Ws[64][33];
    const int tid = threadIdx.x;
    const int bm = blockIdx.y * 64;
    const int bn = blockIdx.x * 64;
    const int tx = tid & 15, ty = tid >> 4;
    float acc[4][4] = {};
    for (int k0 = 0; k0 < 512; k0 += 32) {
        #pragma unroll
        for (int i = tid; i < 64 * 32; i += 256) {
            int r = i >> 5, c = i & 31;
            int m = bm + r, k = k0 + c;
            int t = m & (L_SEQ - 1);
            float v;
            if (k < 256) v = (t > 0) ? x[(size_t)(m - 1) * CH + k] : 0.0f;
            else         v = x[(size_t)m * CH + (k - 256)];
            As[r][c] = v;
        }
        #pragma unroll
        for (int i = tid; i < 64 * 32; i += 256) {
            int r = i >> 5, c = i & 31;
            int n = bn + r, k = k0 + c;
            float v = (k < 256) ? sw[(size_t)n * 512 + k * 2]
                                : sw[(size_t)n * 512 + (k - 256) * 2 + 1];
            Ws[r][c] = v;
        }
        __syncthreads();
        #pragma unroll
        for (int kk = 0; kk < 32; ++kk) {
            float a[4], w[4];
            #pragma unroll
            for (int i = 0; i < 4; ++i) a[i] = As[ty * 4 + i][kk];
            #pragma unroll
            for (int j = 0; j < 4; ++j) w[j] = Ws[tx * 4 + j][kk];
            #pragma unroll
            for (int i = 0; i < 4; ++i)
                #pragma unroll
                for (int j = 0; j < 4; ++j)
                    acc[i][j] += a[i] * w[j];
        }
        __syncthreads();
    }
    #pragma unroll
    for (int i = 0; i < 4; ++i) {
        int m = bm + ty * 4 + i;
        #pragma unroll
        for (int j = 0; j < 4; ++j) {
            int n = bn + tx * 4 + j;
            out[(size_t)m * CH + n] = acc[i][j] + sb[n];
        }
    }
}

// ---------------------------------------------------------------------------
// width[row] = sigmoid(h[row]·ww + wb)*8 + 0.5   (one wave per row)
// ---------------------------------------------------------------------------
__global__ __launch_bounds__(256) void width_kernel(
    const float* __restrict__ h, const float* __restrict__ ww,
    const float* __restrict__ wb, float* __restrict__ width)
{
    const int lane = threadIdx.x & 63;
    const int row = blockIdx.x * 4 + (threadIdx.x >> 6);
    const float4 hv = *((const float4*)(h + (size_t)row * CH) + lane);
    const float4 wv = *((const float4*)ww + lane);
    float part = hv.x * wv.x + hv.y * wv.y + hv.z * wv.z + hv.w * wv.w;
    #pragma unroll
    for (int m = 1; m < 64; m <<= 1) part += __shfl_xor(part, m, 64);
    if (lane == 0) width[row] = sigmoidf_(part + wb[0]) * 8.0f + 0.5f;
}

// ---------------------------------------------------------------------------
// Local attention, one wave per position. qkv rows are 768 wide (q|k|v).
// Writes (o + v) into ov (row-major (rows, 256)).
// ---------------------------------------------------------------------------
__global__ __launch_bounds__(256) void attn_kernel(
    const float* __restrict__ qkv, const float* __restrict__ width,
    float* __restrict__ ov, int l, int lshift)
{
    const int lane = threadIdx.x & 63;
    const int row = blockIdx.x * 4 + (threadIdx.x >> 6);
    const int t = row & (l - 1);
    const size_t base = (size_t)(row - t) * 768;  // b * l * 768

    const float4 q = *((const float4*)(qkv + (size_t)row * 768) + lane);
    const float wdt = width[row];

    float sc[17];
    float mx = -1e30f;
    #pragma unroll
    for (int w = 0; w < 17; ++w) {
        int tt = t + w - 8;
        float part = 0.0f;
        if (tt >= 0 && tt < l) {
            float4 k4 = *((const float4*)(qkv + base + (size_t)tt * 768 + 256) + lane);
            part = q.x * k4.x + q.y * k4.y + q.z * k4.z + q.w * k4.w;
        }
        #pragma unroll
        for (int m = 1; m < 64; m <<= 1) part += __shfl_xor(part, m, 64);
        float dist = fabsf((float)w - 8.0f);
        float sm = sigmoidf_((wdt - dist) * 5.0f);
        float s = part * 0.0625f - (1.0f - sm) * 10000.0f;
        sc[w] = s;
        mx = fmaxf(mx, s);
    }
    float denom = 0.0f;
    #pragma unroll
    for (int w = 0; w < 17; ++w) { sc[w] = expf(sc[w] - mx); denom += sc[w]; }
    const float inv = 1.0f / denom;

    float4 o = make_float4(0.f, 0.f, 0.f, 0.f);
    #pragma unroll
    for (int w = 0; w < 17; ++w) {
        int tt = t + w - 8;
        if (tt >= 0 && tt < l) {
            float4 v4 = *((const float4*)(qkv + base + (size_t)tt * 768 + 512) + lane);
            float aw = sc[w] * inv;
            o.x += aw * v4.x; o.y += aw * v4.y; o.z += aw * v4.z; o.w += aw * v4.w;
        }
    }
    const float4 vt = *((const float4*)(qkv + (size_t)row * 768 + 512) + lane);
    o.x += vt.x; o.y += vt.y; o.z += vt.z; o.w += vt.w;
    *((float4*)(ov + (size_t)row * CH) + lane) = o;
}

// ---------------------------------------------------------------------------
// Mean-pool pairs: out[r] = 0.5*(in[2r] + in[2r+1]) over C-wide rows.
// ---------------------------------------------------------------------------
__global__ void downsample_kernel(const float* __restrict__ in,
                                  float* __restrict__ out, int total)
{
    int idx = blockIdx.x * 256 + threadIdx.x;
    if (idx >= total) return;
    int c = idx & (CH - 1);
    int r = idx >> 8;
    out[idx] = 0.5f * (in[(size_t)(2 * r) * CH + c] + in[(size_t)(2 * r + 1) * CH + c]);
}

// ---------------------------------------------------------------------------
// s[b,t] = sum_lev levels[lev][b, t>>lev, :] · query[lev*256 : lev*256+256]
// one wave per (b,t)
// ---------------------------------------------------------------------------
__global__ __launch_bounds__(256) void gattn_score_kernel(
    const float* __restrict__ l0, const float* __restrict__ l1,
    const float* __restrict__ l2, const float* __restrict__ l3,
    const float* __restrict__ query, float* __restrict__ s)
{
    const int lane = threadIdx.x & 63;
    const int row = blockIdx.x * 4 + (threadIdx.x >> 6);
    const int b = row >> 13;
    const int t = row & (L_SEQ - 1);
    const float* levp[4] = {l0, l1, l2, l3};
    float part = 0.0f;
    #pragma unroll
    for (int lev = 0; lev < 4; ++lev) {
        const float* lp = levp[lev] + ((size_t)b * (L_SEQ >> lev) + (t >> lev)) * CH;
        float4 hv = *((const float4*)lp + lane);
        float4 qv = *((const float4*)(query + lev * CH) + lane);
        part += hv.x * qv.x + hv.y * qv.y + hv.z * qv.z + hv.w * qv.w;
    }
    #pragma unroll
    for (int m = 1; m < 64; m <<= 1) part += __shfl_xor(part, m, 64);
    if (lane == 0) s[row] = part;
}

// ---------------------------------------------------------------------------
// Softmax over L per batch. grid = B, block = 256.
// ---------------------------------------------------------------------------
__global__ __launch_bounds__(256) void softmax_L_kernel(
    const float* __restrict__ s, float* __restrict__ p)
{
    __shared__ float red[256];
    const int b = blockIdx.x, tid = threadIdx.x;
    const float* sb = s + (size_t)b * L_SEQ;
    float mx = -1e30f;
    for (int i = tid; i < L_SEQ; i += 256) mx = fmaxf(mx, sb[i]);
    red[tid] = mx; __syncthreads();
    for (int o = 128; o > 0; o >>= 1) {
        if (tid < o) red[tid] = fmaxf(red[tid], red[tid + o]);
        __syncthreads();
    }
    mx = red[0]; __syncthreads();
    float sum = 0.0f;
    for (int i = tid; i < L_SEQ; i += 256) sum += expf(sb[i] - mx);
    red[tid] = sum; __syncthreads();
    for (int o = 128; o > 0; o >>= 1) {
        if (tid < o) red[tid] += red[tid + o];
        __syncthreads();
    }
    const float inv = 1.0f / red[0];
    for (int i = tid; i < L_SEQ; i += 256) p[(size_t)b * L_SEQ + i] = expf(sb[i] - mx) * inv;
}

// ---------------------------------------------------------------------------
// Partial global-context: grid (16 chunks, B), block 1024 (d = lev*256+c).
// partials[(b*16+chunk)*1024 + d] = sum_{t in chunk} p[b,t]*lev[b, t>>lev, c]
// ---------------------------------------------------------------------------
__global__ __launch_bounds__(1024) void ctx_partial_kernel(
    const float* __restrict__ p,
    const float* __restrict__ l0, const float* __restrict__ l1,
    const float* __restrict__ l2, const float* __restrict__ l3,
    float* __restrict__ partials)
{
    const int d = threadIdx.x;
    const int lev = d >> 8, c = d & 255;
    const int chunk = blockIdx.x, b = blockIdx.y;
    const float* lp = (lev == 0) ? l0 : (lev == 1) ? l1 : (lev == 2) ? l2 : l3;
    lp += (size_t)b * (L_SEQ >> lev) * CH;
    const float* pb = p + (size_t)b * L_SEQ;
    float acc = 0.0f;
    const int t0 = chunk * 512;
    #pragma unroll 4
    for (int t = t0; t < t0 + 512; ++t)
        acc += pb[t] * lp[(size_t)(t >> lev) * CH + c];
    partials[(size_t)(b * 16 + chunk) * 1024 + d] = acc;
}

__global__ void ctx_reduce_kernel(const float* __restrict__ partials,
                                  float* __restrict__ ctx)
{
    const int b = blockIdx.x, d = threadIdx.x;
    float acc = 0.0f;
    #pragma unroll
    for (int c = 0; c < 16; ++c) acc += partials[(size_t)(b * 16 + c) * 1024 + d];
    ctx[b * 1024 + d] = acc;
}

// ---------------------------------------------------------------------------
// film[b,j] = ctx[b,:]·film_w[j,:] + film_b[j]. grid = B, block = 512.
// ---------------------------------------------------------------------------
__global__ __launch_bounds__(512) void film_kernel(
    const float* __restrict__ ctx, const float* __restrict__ fw,
    const float* __restrict__ fb, float* __restrict__ film)
{
    __shared__ float cs[1024];
    const int b = blockIdx.x, j = threadIdx.x;
    cs[j] = ctx[b * 1024 + j];
    cs[j + 512] = ctx[b * 1024 + j + 512];
    __syncthreads();
    float acc = fb[j];
    const float* wr = fw + (size_t)j * 1024;
    #pragma unroll 4
    for (int d = 0; d < 1024; ++d) acc += cs[d] * wr[d];
    film[b * 512 + j] = acc;
}

// ---------------------------------------------------------------------------
// out = lev0 * (1 + scale_f) + bias_f
// ---------------------------------------------------------------------------
__global__ void final_kernel(const float* __restrict__ lev0,
                             const float* __restrict__ film,
                             float* __restrict__ out)
{
    size_t n = (size_t)blockIdx.x * 256 + threadIdx.x;
    int c = (int)(n & (CH - 1));
    int b = (int)(n >> 21);  // L*C = 2^21
    float s = film[b * 512 + c];
    float bi = film[b * 512 + 256 + c];
    out[n] = lev0[n] * (1.0f + s) + bi;
}

extern "C" void kernel_launch(void* const* d_in, const int* in_sizes, int n_in,
                              void* d_out, int out_size, void* d_ws, size_t ws_size,
                              hipStream_t stream) {
    const float* x       = (const float*)d_in[0];
    const float* stem_w  = (const float*)d_in[1];
    const float* stem_b  = (const float*)d_in[2];
    const float* qkv_w   = (const float*)d_in[3];
    const float* width_w = (const float*)d_in[4];
    const float* width_b = (const float*)d_in[5];
    const float* out_w   = (const float*)d_in[6];
    const float* query   = (const float*)d_in[7];
    const float* film_w  = (const float*)d_in[8];
    const float* film_b  = (const float*)d_in[9];
    float* out = (float*)d_out;
    float* ws  = (float*)d_ws;

    // workspace layout (floats)
    float* h_in  = ws;                                      // B*L*C      (also (o+v) buffer)
    float* qkv   = h_in + (size_t)B_SZ * L_SEQ * CH;        // B*L*3C
    float* width = qkv + (size_t)B_SZ * L_SEQ * 3 * CH;     // B*L
    float* lev[4];
    lev[0] = width + (size_t)B_SZ * L_SEQ;
    lev[1] = lev[0] + (size_t)B_SZ * L_SEQ * CH;
    lev[2] = lev[1] + (size_t)B_SZ * (L_SEQ / 2) * CH;
    lev[3] = lev[2] + (size_t)B_SZ * (L_SEQ / 4) * CH;
    float* sbuf = lev[3] + (size_t)B_SZ * (L_SEQ / 8) * CH;
    float* pbuf = sbuf + (size_t)B_SZ * L_SEQ;
    float* partials = pbuf + (size_t)B_SZ * L_SEQ;          // B*16*1024
    float* ctx  = partials + (size_t)B_SZ * 16 * 1024;      // B*1024
    float* film = ctx + (size_t)B_SZ * 1024;                // B*512

    // 1) stem conv as GEMM
    stem_gemm<<<dim3(CH / 64, B_SZ * L_SEQ / 64), 256, 0, stream>>>(x, stem_w, stem_b, h_in);

    // 2) hierarchy levels
    for (int i = 0; i < NLEV; ++i) {
        const int l = L_SEQ >> i;
        const int M = B_SZ * l;
        int lshift = 13 - i;  // log2(l)
        gemm_abt<<<dim3(768 / 64, M / 64), 256, 0, stream>>>(h_in, qkv_w, qkv, M, 768, CH, nullptr);
        width_kernel<<<M / 4, 256, 0, stream>>>(h_in, width_w, width_b, width);
        attn_kernel<<<M / 4, 256, 0, stream>>>(qkv, width, h_in, l, lshift);  // writes (o+v) into h_in
        gemm_abt<<<dim3(CH / 64, M / 64), 256, 0, stream>>>(h_in, out_w, lev[i], M, CH, CH, nullptr);
        if (i < NLEV - 1) {
            int total = (M / 2) * CH;
            downsample_kernel<<<(total + 255) / 256, 256, 0, stream>>>(lev[i], h_in, total);
        }
    }

    // 3) global attention scores + softmax over L
    gattn_score_kernel<<<B_SZ * L_SEQ / 4, 256, 0, stream>>>(lev[0], lev[1], lev[2], lev[3], query, sbuf);
    softmax_L_kernel<<<B_SZ, 256, 0, stream>>>(sbuf, pbuf);

    // 4) global context + FiLM
    ctx_partial_kernel<<<dim3(16, B_SZ), 1024, 0, stream>>>(pbuf, lev[0], lev[1], lev[2], lev[3], partials);
    ctx_reduce_kernel<<<B_SZ, 1024, 0, stream>>>(partials, ctx);
    film_kernel<<<B_SZ, 512, 0, stream>>>(ctx, film_w, film_b, film);

    // 5) output
    final_kernel<<<(B_SZ * L_SEQ * CH) / 256, 256, 0, stream>>>(lev[0], film, out);
}

// Round 2
// 530.167 us; speedup vs baseline: 2.2648x; 2.2648x over previous
//
#include <hip/hip_runtime.h>
#include <math.h>

#define L_SEQ 8192
#define B_SZ  2
#define CH    256
#define NLEV  4

typedef __attribute__((ext_vector_type(8))) short bf16x8;
typedef __attribute__((ext_vector_type(4))) float f32x4;

static __device__ __forceinline__ float sigmoidf_(float x) {
    return 1.0f / (1.0f + expf(-x));
}

// bf16 (stored as ushort) <-> fp32 helpers. bf2f is exact; f2b is RNE
// (matches __float2bfloat16; values here are finite so no NaN handling).
static __device__ __forceinline__ float bf2f_(unsigned short u) {
    union { unsigned int ui; float f; } x;
    x.ui = ((unsigned int)u) << 16;
    return x.f;
}
static __device__ __forceinline__ unsigned short f2b_(float f) {
    union { float f; unsigned int u; } x;
    x.f = f;
    unsigned int lsb = (x.u >> 16) & 1u;
    unsigned int r = x.u + 0x7fffu + lsb;
    return (unsigned short)(r >> 16);
}
static __device__ __forceinline__ float4 ldb4_(const unsigned short* p) {
    ushort4 u = *(const ushort4*)p;
    return make_float4(bf2f_(u.x), bf2f_(u.y), bf2f_(u.z), bf2f_(u.w));
}

// ---------------------------------------------------------------------------
// MFMA bf16 GEMM (m97 structure): out[m,n] = sum_k A[m,k]*W[n,k] (+bias[n]).
// A: (M,Kd) bf16 row-major. W: (N,Kd) bf16 row-major. Writes fp32 and/or
// bf16 outputs. 128x128 tile, 4 waves, BK=32, global_load_lds width=16.
// Requires M%128==0, N%128==0, Kd%32==0, 16B-aligned pointers.
// ---------------------------------------------------------------------------
__global__ __launch_bounds__(256) void gemm_bf16(
    const unsigned short* __restrict__ A, const unsigned short* __restrict__ W,
    float* __restrict__ outF, unsigned short* __restrict__ outB,
    int M, int N, int Kd, const float* __restrict__ bias)
{
    __shared__ unsigned short As[128 * 32];
    __shared__ unsigned short Bs[128 * 32];
    const int tid  = threadIdx.x;
    const int wave = tid >> 6;
    const int lane = tid & 63;
    const int bm = blockIdx.y * 128;
    const int bn = blockIdx.x * 128;
    const int wm = (wave & 1) * 64;   // wave's 64x64 quadrant
    const int wn = (wave >> 1) * 64;

    // staging: lane i of a chunk loads row (i>>2), cols (i&3)*8..+8  (16B)
    const int srow = lane >> 2;
    const int scol = (lane & 3) * 8;

    f32x4 acc[4][4] = {};

    for (int k0 = 0; k0 < Kd; k0 += 32) {
        __syncthreads();  // LDS reads from previous iter done
        #pragma unroll
        for (int c = 0; c < 2; ++c) {
            const int chunk = c * 4 + wave;          // 0..7, 16 rows each
            const int row = chunk * 16 + srow;
            const unsigned short* ga = A + (size_t)(bm + row) * Kd + k0 + scol;
            const unsigned short* gw = W + (size_t)(bn + row) * Kd + k0 + scol;
            // LDS dst: wave-uniform base + lane*16B == row-major [128][32] bf16
            __builtin_amdgcn_global_load_lds(
                (const __attribute__((address_space(1))) void*)ga,
                (__attribute__((address_space(3))) void*)(As + chunk * 16 * 32),
                16, 0, 0);
            __builtin_amdgcn_global_load_lds(
                (const __attribute__((address_space(1))) void*)gw,
                (__attribute__((address_space(3))) void*)(Bs + chunk * 16 * 32),
                16, 0, 0);
        }
        __syncthreads();  // compiler drains vmcnt before s_barrier

        bf16x8 af[4], bf[4];
        const int fr = lane & 15;
        const int kk = (lane >> 4) * 8;
        #pragma unroll
        for (int i = 0; i < 4; ++i) {
            af[i] = *(const bf16x8*)(As + (wm + i * 16 + fr) * 32 + kk);
            bf[i] = *(const bf16x8*)(Bs + (wn + i * 16 + fr) * 32 + kk);
        }
        #pragma unroll
        for (int i = 0; i < 4; ++i)
            #pragma unroll
            for (int j = 0; j < 4; ++j)
                acc[i][j] = __builtin_amdgcn_mfma_f32_16x16x32_bf16(
                    af[i], bf[j], acc[i][j], 0, 0, 0);
    }

    // C/D layout: col = lane&15, row = (lane>>4)*4 + reg
    const int cn = lane & 15;
    const int cr = (lane >> 4) * 4;
    #pragma unroll
    for (int i = 0; i < 4; ++i) {
        #pragma unroll
        for (int r = 0; r < 4; ++r) {
            const int m = bm + wm + i * 16 + cr + r;
            const size_t rowoff = (size_t)m * N;
            #pragma unroll
            for (int j = 0; j < 4; ++j) {
                const int n = bn + wn + j * 16 + cn;
                float v = acc[i][j][r];
                if (bias) v += bias[n];
                if (outF) outF[rowoff + n] = v;
                if (outB) outB[rowoff + n] = f2b_(v);
            }
        }
    }
}

// ---------------------------------------------------------------------------
// Prep kernels: fp32 -> bf16
// ---------------------------------------------------------------------------
__global__ void f2b_kernel(const float* __restrict__ in,
                           unsigned short* __restrict__ out, int n)
{
    int i = blockIdx.x * 256 + threadIdx.x;
    if (i < n) out[i] = f2b_(in[i]);
}

// stem A: (M,512) bf16; cols 0-255 = x[t-1] (0 at t==0), cols 256-511 = x[t]
__global__ void stem_prep(const float* __restrict__ x,
                          unsigned short* __restrict__ As)
{
    size_t idx = (size_t)blockIdx.x * 256 + threadIdx.x;  // M*512
    int k = (int)(idx & 511);
    size_t m = idx >> 9;
    int t = (int)(m & (L_SEQ - 1));
    float v;
    if (k < 256) v = (t > 0) ? x[(m - 1) * CH + k] : 0.0f;
    else         v = x[m * CH + (k - 256)];
    As[idx] = f2b_(v);
}

// stem W: (256,512) bf16; Ws[n,k] = sw[n,k,0] for k<256 else sw[n,k-256,1]
__global__ void stem_wprep(const float* __restrict__ sw,
                           unsigned short* __restrict__ Ws)
{
    int idx = blockIdx.x * 256 + threadIdx.x;  // 256*512
    int k = idx & 511, n = idx >> 9;
    float v = (k < 256) ? sw[(size_t)n * 512 + k * 2]
                        : sw[(size_t)n * 512 + (k - 256) * 2 + 1];
    Ws[idx] = f2b_(v);
}

// ---------------------------------------------------------------------------
// width[row] = sigmoid(h[row]·ww + wb)*8 + 0.5   (one wave per row, fp32 h)
// ---------------------------------------------------------------------------
__global__ __launch_bounds__(256) void width_kernel(
    const float* __restrict__ h, const float* __restrict__ ww,
    const float* __restrict__ wb, float* __restrict__ width)
{
    const int lane = threadIdx.x & 63;
    const int row = blockIdx.x * 4 + (threadIdx.x >> 6);
    const float4 hv = *((const float4*)(h + (size_t)row * CH) + lane);
    const float4 wv = *((const float4*)ww + lane);
    float part = hv.x * wv.x + hv.y * wv.y + hv.z * wv.z + hv.w * wv.w;
    #pragma unroll
    for (int m = 1; m < 64; m <<= 1) part += __shfl_xor(part, m, 64);
    if (lane == 0) width[row] = sigmoidf_(part + wb[0]) * 8.0f + 0.5f;
}

// ---------------------------------------------------------------------------
// Local attention, one wave per position, bf16 qkv in, bf16 (o+v) out.
// ---------------------------------------------------------------------------
__global__ __launch_bounds__(256) void attn_kernel(
    const unsigned short* __restrict__ qkv, const float* __restrict__ width,
    unsigned short* __restrict__ ov, int l)
{
    const int lane = threadIdx.x & 63;
    const int row = blockIdx.x * 4 + (threadIdx.x >> 6);
    const int t = row & (l - 1);
    const size_t base = (size_t)(row - t) * 768;  // batch base

    const float4 q = ldb4_(qkv + (size_t)row * 768 + lane * 4);
    const float wdt = width[row];

    float sc[17];
    float mx = -1e30f;
    #pragma unroll
    for (int w = 0; w < 17; ++w) {
        int tt = t + w - 8;
        float part = 0.0f;
        if (tt >= 0 && tt < l) {
            float4 k4 = ldb4_(qkv + base + (size_t)tt * 768 + 256 + lane * 4);
            part = q.x * k4.x + q.y * k4.y + q.z * k4.z + q.w * k4.w;
        }
        #pragma unroll
        for (int m = 1; m < 64; m <<= 1) part += __shfl_xor(part, m, 64);
        float dist = fabsf((float)w - 8.0f);
        float sm = sigmoidf_((wdt - dist) * 5.0f);
        float s = part * 0.0625f - (1.0f - sm) * 10000.0f;
        sc[w] = s;
        mx = fmaxf(mx, s);
    }
    float denom = 0.0f;
    #pragma unroll
    for (int w = 0; w < 17; ++w) { sc[w] = expf(sc[w] - mx); denom += sc[w]; }
    const float inv = 1.0f / denom;

    float4 o = make_float4(0.f, 0.f, 0.f, 0.f);
    #pragma unroll
    for (int w = 0; w < 17; ++w) {
        int tt = t + w - 8;
        if (tt >= 0 && tt < l) {
            float4 v4 = ldb4_(qkv + base + (size_t)tt * 768 + 512 + lane * 4);
            float aw = sc[w] * inv;
            o.x += aw * v4.x; o.y += aw * v4.y; o.z += aw * v4.z; o.w += aw * v4.w;
        }
    }
    const float4 vt = ldb4_(qkv + (size_t)row * 768 + 512 + lane * 4);
    o.x += vt.x; o.y += vt.y; o.z += vt.z; o.w += vt.w;
    ushort4 st;
    st.x = f2b_(o.x); st.y = f2b_(o.y); st.z = f2b_(o.z); st.w = f2b_(o.w);
    *(ushort4*)(ov + (size_t)row * CH + lane * 4) = st;
}

// ---------------------------------------------------------------------------
// Mean-pool pairs -> next level h (fp32 + bf16)
// ---------------------------------------------------------------------------
__global__ void downsample_kernel(const float* __restrict__ in,
                                  float* __restrict__ out32,
                                  unsigned short* __restrict__ out16, int total)
{
    int idx = blockIdx.x * 256 + threadIdx.x;
    if (idx >= total) return;
    int c = idx & (CH - 1);
    int r = idx >> 8;
    float v = 0.5f * (in[(size_t)(2 * r) * CH + c] + in[(size_t)(2 * r + 1) * CH + c]);
    out32[idx] = v;
    out16[idx] = f2b_(v);
}

// ---------------------------------------------------------------------------
// s[b,t] = sum_lev levels[lev][b, t>>lev, :]·query[lev*256:+256] (wave/(b,t))
// ---------------------------------------------------------------------------
__global__ __launch_bounds__(256) void gattn_score_kernel(
    const float* __restrict__ l0, const float* __restrict__ l1,
    const float* __restrict__ l2, const float* __restrict__ l3,
    const float* __restrict__ query, float* __restrict__ s)
{
    const int lane = threadIdx.x & 63;
    const int row = blockIdx.x * 4 + (threadIdx.x >> 6);
    const int b = row >> 13;
    const int t = row & (L_SEQ - 1);
    const float* levp[4] = {l0, l1, l2, l3};
    float part = 0.0f;
    #pragma unroll
    for (int lev = 0; lev < 4; ++lev) {
        const float* lp = levp[lev] + ((size_t)b * (L_SEQ >> lev) + (t >> lev)) * CH;
        float4 hv = *((const float4*)lp + lane);
        float4 qv = *((const float4*)(query + lev * CH) + lane);
        part += hv.x * qv.x + hv.y * qv.y + hv.z * qv.z + hv.w * qv.w;
    }
    #pragma unroll
    for (int m = 1; m < 64; m <<= 1) part += __shfl_xor(part, m, 64);
    if (lane == 0) s[row] = part;
}

__global__ __launch_bounds__(256) void softmax_L_kernel(
    const float* __restrict__ s, float* __restrict__ p)
{
    __shared__ float red[256];
    const int b = blockIdx.x, tid = threadIdx.x;
    const float* sb = s + (size_t)b * L_SEQ;
    float mx = -1e30f;
    for (int i = tid; i < L_SEQ; i += 256) mx = fmaxf(mx, sb[i]);
    red[tid] = mx; __syncthreads();
    for (int o = 128; o > 0; o >>= 1) {
        if (tid < o) red[tid] = fmaxf(red[tid], red[tid + o]);
        __syncthreads();
    }
    mx = red[0]; __syncthreads();
    float sum = 0.0f;
    for (int i = tid; i < L_SEQ; i += 256) sum += expf(sb[i] - mx);
    red[tid] = sum; __syncthreads();
    for (int o = 128; o > 0; o >>= 1) {
        if (tid < o) red[tid] += red[tid + o];
        __syncthreads();
    }
    const float inv = 1.0f / red[0];
    for (int i = tid; i < L_SEQ; i += 256) p[(size_t)b * L_SEQ + i] = expf(sb[i] - mx) * inv;
}

__global__ __launch_bounds__(1024) void ctx_partial_kernel(
    const float* __restrict__ p,
    const float* __restrict__ l0, const float* __restrict__ l1,
    const float* __restrict__ l2, const float* __restrict__ l3,
    float* __restrict__ partials)
{
    const int d = threadIdx.x;
    const int lev = d >> 8, c = d & 255;
    const int chunk = blockIdx.x, b = blockIdx.y;
    const float* lp = (lev == 0) ? l0 : (lev == 1) ? l1 : (lev == 2) ? l2 : l3;
    lp += (size_t)b * (L_SEQ >> lev) * CH;
    const float* pb = p + (size_t)b * L_SEQ;
    float acc = 0.0f;
    const int t0 = chunk * 512;
    #pragma unroll 4
    for (int t = t0; t < t0 + 512; ++t)
        acc += pb[t] * lp[(size_t)(t >> lev) * CH + c];
    partials[(size_t)(b * 16 + chunk) * 1024 + d] = acc;
}

__global__ void ctx_reduce_kernel(const float* __restrict__ partials,
                                  float* __restrict__ ctx)
{
    const int b = blockIdx.x, d = threadIdx.x;
    float acc = 0.0f;
    #pragma unroll
    for (int c = 0; c < 16; ++c) acc += partials[(size_t)(b * 16 + c) * 1024 + d];
    ctx[b * 1024 + d] = acc;
}

__global__ __launch_bounds__(512) void film_kernel(
    const float* __restrict__ ctx, const float* __restrict__ fw,
    const float* __restrict__ fb, float* __restrict__ film)
{
    __shared__ float cs[1024];
    const int b = blockIdx.x, j = threadIdx.x;
    cs[j] = ctx[b * 1024 + j];
    cs[j + 512] = ctx[b * 1024 + j + 512];
    __syncthreads();
    float acc = fb[j];
    const float* wr = fw + (size_t)j * 1024;
    #pragma unroll 4
    for (int d = 0; d < 1024; ++d) acc += cs[d] * wr[d];
    film[b * 512 + j] = acc;
}

__global__ void final_kernel(const float* __restrict__ lev0,
                             const float* __restrict__ film,
                             float* __restrict__ out)
{
    size_t n = (size_t)blockIdx.x * 256 + threadIdx.x;
    int c = (int)(n & (CH - 1));
    int b = (int)(n >> 21);  // L*C = 2^21
    float s = film[b * 512 + c];
    float bi = film[b * 512 + 256 + c];
    out[n] = lev0[n] * (1.0f + s) + bi;
}

extern "C" void kernel_launch(void* const* d_in, const int* in_sizes, int n_in,
                              void* d_out, int out_size, void* d_ws, size_t ws_size,
                              hipStream_t stream) {
    const float* x       = (const float*)d_in[0];
    const float* stem_w  = (const float*)d_in[1];
    const float* stem_b  = (const float*)d_in[2];
    const float* qkv_w   = (const float*)d_in[3];
    const float* width_w = (const float*)d_in[4];
    const float* width_b = (const float*)d_in[5];
    const float* out_w   = (const float*)d_in[6];
    const float* query   = (const float*)d_in[7];
    const float* film_w  = (const float*)d_in[8];
    const float* film_b  = (const float*)d_in[9];
    float* out = (float*)d_out;
    float* ws  = (float*)d_ws;

    // ---- workspace layout (fp32 region then bf16 region) ----
    float* h32      = ws;                       // 4,194,304
    float* width    = h32 + 4194304;            // 16,384
    float* lev[4];
    lev[0] = width + 16384;                     // 4,194,304
    lev[1] = lev[0] + 4194304;                  // 2,097,152
    lev[2] = lev[1] + 2097152;                  // 1,048,576
    lev[3] = lev[2] + 1048576;                  // 524,288
    float* sbuf     = lev[3] + 524288;          // 16,384
    float* pbuf     = sbuf + 16384;             // 16,384
    float* partials = pbuf + 16384;             // 32,768
    float* ctx      = partials + 32768;         // 2,048
    float* film     = ctx + 2048;               // 1,024
    unsigned short* h16   = (unsigned short*)(film + 1024);  // 4,194,304
    unsigned short* qkv16 = h16 + 4194304;      // 12,582,912 (stem-A aliases here)
    unsigned short* ov16  = qkv16 + 12582912;   // 4,194,304
    unsigned short* qw16  = ov16 + 4194304;     // 196,608
    unsigned short* ow16  = qw16 + 196608;      // 65,536
    unsigned short* sw16  = ow16 + 65536;       // 131,072

    // ---- weight + stem-A prep (bf16) ----
    f2b_kernel<<<(196608 + 255) / 256, 256, 0, stream>>>(qkv_w, qw16, 196608);
    f2b_kernel<<<(65536 + 255) / 256, 256, 0, stream>>>(out_w, ow16, 65536);
    stem_wprep<<<(131072 + 255) / 256, 256, 0, stream>>>(stem_w, sw16);
    unsigned short* stemA = qkv16;  // dead before qkv16 is first written
    stem_prep<<<(B_SZ * L_SEQ * 512) / 256, 256, 0, stream>>>(x, stemA);

    // ---- stem conv as bf16 GEMM -> h (fp32 + bf16) ----
    gemm_bf16<<<dim3(CH / 128, B_SZ * L_SEQ / 128), 256, 0, stream>>>(
        stemA, sw16, h32, h16, B_SZ * L_SEQ, CH, 512, stem_b);

    // ---- hierarchy levels ----
    for (int i = 0; i < NLEV; ++i) {
        const int l = L_SEQ >> i;
        const int M = B_SZ * l;
        gemm_bf16<<<dim3(768 / 128, M / 128), 256, 0, stream>>>(
            h16, qw16, nullptr, qkv16, M, 768, CH, nullptr);
        width_kernel<<<M / 4, 256, 0, stream>>>(h32, width_w, width_b, width);
        attn_kernel<<<M / 4, 256, 0, stream>>>(qkv16, width, ov16, l);
        gemm_bf16<<<dim3(CH / 128, M / 128), 256, 0, stream>>>(
            ov16, ow16, lev[i], nullptr, M, CH, CH, nullptr);
        if (i < NLEV - 1) {
            int total = (M / 2) * CH;
            downsample_kernel<<<(total + 255) / 256, 256, 0, stream>>>(
                lev[i], h32, h16, total);
        }
    }

    // ---- global attention + FiLM (fp32 tail) ----
    gattn_score_kernel<<<B_SZ * L_SEQ / 4, 256, 0, stream>>>(
        lev[0], lev[1], lev[2], lev[3], query, sbuf);
    softmax_L_kernel<<<B_SZ, 256, 0, stream>>>(sbuf, pbuf);
    ctx_partial_kernel<<<dim3(16, B_SZ), 1024, 0, stream>>>(
        pbuf, lev[0], lev[1], lev[2], lev[3], partials);
    ctx_reduce_kernel<<<B_SZ, 1024, 0, stream>>>(partials, ctx);
    film_kernel<<<B_SZ, 512, 0, stream>>>(ctx, film_w, film_b, film);
    final_kernel<<<(B_SZ * L_SEQ * CH) / 256, 256, 0, stream>>>(lev[0], film, out);
}

// Round 3
// 432.212 us; speedup vs baseline: 2.7781x; 1.2266x over previous
//
#include <hip/hip_runtime.h>
#include <math.h>

#define L_SEQ 8192
#define B_SZ  2
#define CH    256
#define NLEV  4

typedef __attribute__((ext_vector_type(8))) short bf16x8;
typedef __attribute__((ext_vector_type(4))) float f32x4;

static __device__ __forceinline__ float sigmoidf_(float x) {
    return 1.0f / (1.0f + expf(-x));
}

// bf16 (stored as ushort) <-> fp32 helpers. bf2f is exact; f2b is RNE.
static __device__ __forceinline__ float bf2f_(unsigned short u) {
    union { unsigned int ui; float f; } x;
    x.ui = ((unsigned int)u) << 16;
    return x.f;
}
static __device__ __forceinline__ unsigned short f2b_(float f) {
    union { float f; unsigned int u; } x;
    x.f = f;
    unsigned int lsb = (x.u >> 16) & 1u;
    unsigned int r = x.u + 0x7fffu + lsb;
    return (unsigned short)(r >> 16);
}
static __device__ __forceinline__ float4 ldb4_(const unsigned short* p) {
    ushort4 u = *(const ushort4*)p;
    return make_float4(bf2f_(u.x), bf2f_(u.y), bf2f_(u.z), bf2f_(u.w));
}

// ---------------------------------------------------------------------------
// MFMA bf16 GEMM (m97 structure): out[m,n] = sum_k A[m,k]*W[n,k] (+bias[n]).
// 128x128 tile, 4 waves, BK=32, global_load_lds width=16.
// ---------------------------------------------------------------------------
__global__ __launch_bounds__(256) void gemm_bf16(
    const unsigned short* __restrict__ A, const unsigned short* __restrict__ W,
    float* __restrict__ outF, unsigned short* __restrict__ outB,
    int M, int N, int Kd, const float* __restrict__ bias)
{
    __shared__ unsigned short As[128 * 32];
    __shared__ unsigned short Bs[128 * 32];
    const int tid  = threadIdx.x;
    const int wave = tid >> 6;
    const int lane = tid & 63;
    const int bm = blockIdx.y * 128;
    const int bn = blockIdx.x * 128;
    const int wm = (wave & 1) * 64;
    const int wn = (wave >> 1) * 64;

    const int srow = lane >> 2;
    const int scol = (lane & 3) * 8;

    f32x4 acc[4][4] = {};

    for (int k0 = 0; k0 < Kd; k0 += 32) {
        __syncthreads();
        #pragma unroll
        for (int c = 0; c < 2; ++c) {
            const int chunk = c * 4 + wave;
            const int row = chunk * 16 + srow;
            const unsigned short* ga = A + (size_t)(bm + row) * Kd + k0 + scol;
            const unsigned short* gw = W + (size_t)(bn + row) * Kd + k0 + scol;
            __builtin_amdgcn_global_load_lds(
                (const __attribute__((address_space(1))) void*)ga,
                (__attribute__((address_space(3))) void*)(As + chunk * 16 * 32),
                16, 0, 0);
            __builtin_amdgcn_global_load_lds(
                (const __attribute__((address_space(1))) void*)gw,
                (__attribute__((address_space(3))) void*)(Bs + chunk * 16 * 32),
                16, 0, 0);
        }
        __syncthreads();

        bf16x8 af[4], bf[4];
        const int fr = lane & 15;
        const int kk = (lane >> 4) * 8;
        #pragma unroll
        for (int i = 0; i < 4; ++i) {
            af[i] = *(const bf16x8*)(As + (wm + i * 16 + fr) * 32 + kk);
            bf[i] = *(const bf16x8*)(Bs + (wn + i * 16 + fr) * 32 + kk);
        }
        #pragma unroll
        for (int i = 0; i < 4; ++i)
            #pragma unroll
            for (int j = 0; j < 4; ++j)
                acc[i][j] = __builtin_amdgcn_mfma_f32_16x16x32_bf16(
                    af[i], bf[j], acc[i][j], 0, 0, 0);
    }

    const int cn = lane & 15;
    const int cr = (lane >> 4) * 4;
    #pragma unroll
    for (int i = 0; i < 4; ++i) {
        #pragma unroll
        for (int r = 0; r < 4; ++r) {
            const int m = bm + wm + i * 16 + cr + r;
            const size_t rowoff = (size_t)m * N;
            #pragma unroll
            for (int j = 0; j < 4; ++j) {
                const int n = bn + wn + j * 16 + cn;
                float v = acc[i][j][r];
                if (bias) v += bias[n];
                if (outF) outF[rowoff + n] = v;
                if (outB) outB[rowoff + n] = f2b_(v);
            }
        }
    }
}

// ---------------------------------------------------------------------------
// Prep kernels: fp32 -> bf16
// ---------------------------------------------------------------------------
__global__ void f2b_kernel(const float* __restrict__ in,
                           unsigned short* __restrict__ out, int n)
{
    int i = blockIdx.x * 256 + threadIdx.x;
    if (i < n) out[i] = f2b_(in[i]);
}

__global__ void stem_prep(const float* __restrict__ x,
                          unsigned short* __restrict__ As)
{
    size_t idx = (size_t)blockIdx.x * 256 + threadIdx.x;  // M*512
    int k = (int)(idx & 511);
    size_t m = idx >> 9;
    int t = (int)(m & (L_SEQ - 1));
    float v;
    if (k < 256) v = (t > 0) ? x[(m - 1) * CH + k] : 0.0f;
    else         v = x[m * CH + (k - 256)];
    As[idx] = f2b_(v);
}

__global__ void stem_wprep(const float* __restrict__ sw,
                           unsigned short* __restrict__ Ws)
{
    int idx = blockIdx.x * 256 + threadIdx.x;  // 256*512
    int k = idx & 511, n = idx >> 9;
    float v = (k < 256) ? sw[(size_t)n * 512 + k * 2]
                        : sw[(size_t)n * 512 + (k - 256) * 2 + 1];
    Ws[idx] = f2b_(v);
}

// ---------------------------------------------------------------------------
// width[row] = sigmoid(h[row]·ww + wb)*8 + 0.5   (one wave per row, fp32 h)
// ---------------------------------------------------------------------------
__global__ __launch_bounds__(256) void width_kernel(
    const float* __restrict__ h, const float* __restrict__ ww,
    const float* __restrict__ wb, float* __restrict__ width)
{
    const int lane = threadIdx.x & 63;
    const int row = blockIdx.x * 4 + (threadIdx.x >> 6);
    const float4 hv = *((const float4*)(h + (size_t)row * CH) + lane);
    const float4 wv = *((const float4*)ww + lane);
    float part = hv.x * wv.x + hv.y * wv.y + hv.z * wv.z + hv.w * wv.w;
    #pragma unroll
    for (int m = 1; m < 64; m <<= 1) part += __shfl_xor(part, m, 64);
    if (lane == 0) width[row] = sigmoidf_(part + wb[0]) * 8.0f + 0.5f;
}

// ---------------------------------------------------------------------------
// Local attention, one wave per position, bf16 qkv in, bf16 (o+v) out.
// ---------------------------------------------------------------------------
__global__ __launch_bounds__(256) void attn_kernel(
    const unsigned short* __restrict__ qkv, const float* __restrict__ width,
    unsigned short* __restrict__ ov, int l)
{
    const int lane = threadIdx.x & 63;
    const int row = blockIdx.x * 4 + (threadIdx.x >> 6);
    const int t = row & (l - 1);
    const size_t base = (size_t)(row - t) * 768;

    const float4 q = ldb4_(qkv + (size_t)row * 768 + lane * 4);
    const float wdt = width[row];

    float sc[17];
    float mx = -1e30f;
    #pragma unroll
    for (int w = 0; w < 17; ++w) {
        int tt = t + w - 8;
        float part = 0.0f;
        if (tt >= 0 && tt < l) {
            float4 k4 = ldb4_(qkv + base + (size_t)tt * 768 + 256 + lane * 4);
            part = q.x * k4.x + q.y * k4.y + q.z * k4.z + q.w * k4.w;
        }
        #pragma unroll
        for (int m = 1; m < 64; m <<= 1) part += __shfl_xor(part, m, 64);
        float dist = fabsf((float)w - 8.0f);
        float sm = sigmoidf_((wdt - dist) * 5.0f);
        float s = part * 0.0625f - (1.0f - sm) * 10000.0f;
        sc[w] = s;
        mx = fmaxf(mx, s);
    }
    float denom = 0.0f;
    #pragma unroll
    for (int w = 0; w < 17; ++w) { sc[w] = expf(sc[w] - mx); denom += sc[w]; }
    const float inv = 1.0f / denom;

    float4 o = make_float4(0.f, 0.f, 0.f, 0.f);
    #pragma unroll
    for (int w = 0; w < 17; ++w) {
        int tt = t + w - 8;
        if (tt >= 0 && tt < l) {
            float4 v4 = ldb4_(qkv + base + (size_t)tt * 768 + 512 + lane * 4);
            float aw = sc[w] * inv;
            o.x += aw * v4.x; o.y += aw * v4.y; o.z += aw * v4.z; o.w += aw * v4.w;
        }
    }
    const float4 vt = ldb4_(qkv + (size_t)row * 768 + 512 + lane * 4);
    o.x += vt.x; o.y += vt.y; o.z += vt.z; o.w += vt.w;
    ushort4 st;
    st.x = f2b_(o.x); st.y = f2b_(o.y); st.z = f2b_(o.z); st.w = f2b_(o.w);
    *(ushort4*)(ov + (size_t)row * CH + lane * 4) = st;
}

// ---------------------------------------------------------------------------
// Mean-pool pairs -> next level h (fp32 + bf16)
// ---------------------------------------------------------------------------
__global__ void downsample_kernel(const float* __restrict__ in,
                                  float* __restrict__ out32,
                                  unsigned short* __restrict__ out16, int total)
{
    int idx = blockIdx.x * 256 + threadIdx.x;
    if (idx >= total) return;
    int c = idx & (CH - 1);
    int r = idx >> 8;
    float v = 0.5f * (in[(size_t)(2 * r) * CH + c] + in[(size_t)(2 * r + 1) * CH + c]);
    out32[idx] = v;
    out16[idx] = f2b_(v);
}

// ---------------------------------------------------------------------------
// s[b,t] = sum_lev levels[lev][b, t>>lev, :]·query[lev*256:+256] (wave/(b,t))
// ---------------------------------------------------------------------------
__global__ __launch_bounds__(256) void gattn_score_kernel(
    const float* __restrict__ l0, const float* __restrict__ l1,
    const float* __restrict__ l2, const float* __restrict__ l3,
    const float* __restrict__ query, float* __restrict__ s)
{
    const int lane = threadIdx.x & 63;
    const int row = blockIdx.x * 4 + (threadIdx.x >> 6);
    const int b = row >> 13;
    const int t = row & (L_SEQ - 1);
    const float* levp[4] = {l0, l1, l2, l3};
    float part = 0.0f;
    #pragma unroll
    for (int lev = 0; lev < 4; ++lev) {
        const float* lp = levp[lev] + ((size_t)b * (L_SEQ >> lev) + (t >> lev)) * CH;
        float4 hv = *((const float4*)lp + lane);
        float4 qv = *((const float4*)(query + lev * CH) + lane);
        part += hv.x * qv.x + hv.y * qv.y + hv.z * qv.z + hv.w * qv.w;
    }
    #pragma unroll
    for (int m = 1; m < 64; m <<= 1) part += __shfl_xor(part, m, 64);
    if (lane == 0) s[row] = part;
}

// Softmax over L per batch. grid = B, block = 1024.
__global__ __launch_bounds__(1024) void softmax_L_kernel(
    const float* __restrict__ s, float* __restrict__ p)
{
    __shared__ float red[1024];
    const int b = blockIdx.x, tid = threadIdx.x;
    const float* sb = s + (size_t)b * L_SEQ;
    float mx = -1e30f;
    for (int i = tid; i < L_SEQ; i += 1024) mx = fmaxf(mx, sb[i]);
    red[tid] = mx; __syncthreads();
    for (int o = 512; o > 0; o >>= 1) {
        if (tid < o) red[tid] = fmaxf(red[tid], red[tid + o]);
        __syncthreads();
    }
    mx = red[0]; __syncthreads();
    float sum = 0.0f;
    for (int i = tid; i < L_SEQ; i += 1024) sum += expf(sb[i] - mx);
    red[tid] = sum; __syncthreads();
    for (int o = 512; o > 0; o >>= 1) {
        if (tid < o) red[tid] += red[tid + o];
        __syncthreads();
    }
    const float inv = 1.0f / red[0];
    for (int i = tid; i < L_SEQ; i += 1024) p[(size_t)b * L_SEQ + i] = expf(sb[i] - mx) * inv;
}

// ---------------------------------------------------------------------------
// Partial global-context: grid (64 chunks, B), block 1024 (d = lev*256+c).
// partials[(b*64+chunk)*1024 + d] = sum_{t in chunk(128)} p[b,t]*lev[...,c]
// ---------------------------------------------------------------------------
__global__ __launch_bounds__(1024) void ctx_partial_kernel(
    const float* __restrict__ p,
    const float* __restrict__ l0, const float* __restrict__ l1,
    const float* __restrict__ l2, const float* __restrict__ l3,
    float* __restrict__ partials)
{
    const int d = threadIdx.x;
    const int lev = d >> 8, c = d & 255;
    const int chunk = blockIdx.x, b = blockIdx.y;
    const float* lp = (lev == 0) ? l0 : (lev == 1) ? l1 : (lev == 2) ? l2 : l3;
    lp += (size_t)b * (L_SEQ >> lev) * CH;
    const float* pb = p + (size_t)b * L_SEQ;
    float acc = 0.0f;
    const int t0 = chunk * 128;
    #pragma unroll 4
    for (int t = t0; t < t0 + 128; ++t)
        acc += pb[t] * lp[(size_t)(t >> lev) * CH + c];
    partials[(size_t)(b * 64 + chunk) * 1024 + d] = acc;
}

// grid (4, B), block 256: ctx[b*1024+d] = sum over 64 chunks
__global__ __launch_bounds__(256) void ctx_reduce_kernel(
    const float* __restrict__ partials, float* __restrict__ ctx)
{
    const int b = blockIdx.y;
    const int d = blockIdx.x * 256 + threadIdx.x;
    float acc = 0.0f;
    #pragma unroll
    for (int c = 0; c < 64; ++c) acc += partials[(size_t)(b * 64 + c) * 1024 + d];
    ctx[b * 1024 + d] = acc;
}

// ---------------------------------------------------------------------------
// film[b,j] = ctx[b,:]·fw[j,:] + fb[j]. One wave per j, both batches.
// grid = 128 blocks x 256 threads.
// ---------------------------------------------------------------------------
__global__ __launch_bounds__(256) void film_kernel(
    const float* __restrict__ ctx, const float* __restrict__ fw,
    const float* __restrict__ fb, float* __restrict__ film)
{
    const int lane = threadIdx.x & 63;
    const int j = blockIdx.x * 4 + (threadIdx.x >> 6);  // 0..511
    float acc0 = 0.0f, acc1 = 0.0f;
    #pragma unroll
    for (int r = 0; r < 4; ++r) {
        float4 w4 = *((const float4*)(fw + (size_t)j * 1024 + r * 256) + lane);
        float4 c0 = *((const float4*)(ctx + r * 256) + lane);
        float4 c1 = *((const float4*)(ctx + 1024 + r * 256) + lane);
        acc0 += w4.x * c0.x + w4.y * c0.y + w4.z * c0.z + w4.w * c0.w;
        acc1 += w4.x * c1.x + w4.y * c1.y + w4.z * c1.z + w4.w * c1.w;
    }
    #pragma unroll
    for (int m = 1; m < 64; m <<= 1) {
        acc0 += __shfl_xor(acc0, m, 64);
        acc1 += __shfl_xor(acc1, m, 64);
    }
    if (lane == 0) {
        float b = fb[j];
        film[j] = acc0 + b;
        film[512 + j] = acc1 + b;
    }
}

__global__ void final_kernel(const float* __restrict__ lev0,
                             const float* __restrict__ film,
                             float* __restrict__ out)
{
    size_t n = (size_t)blockIdx.x * 256 + threadIdx.x;
    int c = (int)(n & (CH - 1));
    int b = (int)(n >> 21);  // L*C = 2^21
    float s = film[b * 512 + c];
    float bi = film[b * 512 + 256 + c];
    out[n] = lev0[n] * (1.0f + s) + bi;
}

extern "C" void kernel_launch(void* const* d_in, const int* in_sizes, int n_in,
                              void* d_out, int out_size, void* d_ws, size_t ws_size,
                              hipStream_t stream) {
    const float* x       = (const float*)d_in[0];
    const float* stem_w  = (const float*)d_in[1];
    const float* stem_b  = (const float*)d_in[2];
    const float* qkv_w   = (const float*)d_in[3];
    const float* width_w = (const float*)d_in[4];
    const float* width_b = (const float*)d_in[5];
    const float* out_w   = (const float*)d_in[6];
    const float* query   = (const float*)d_in[7];
    const float* film_w  = (const float*)d_in[8];
    const float* film_b  = (const float*)d_in[9];
    float* out = (float*)d_out;
    float* ws  = (float*)d_ws;

    // ---- workspace layout (fp32 region then bf16 region) ----
    float* h32      = ws;                       // 4,194,304
    float* width    = h32 + 4194304;            // 16,384
    float* lev[4];
    lev[0] = width + 16384;                     // 4,194,304
    lev[1] = lev[0] + 4194304;                  // 2,097,152
    lev[2] = lev[1] + 2097152;                  // 1,048,576
    lev[3] = lev[2] + 1048576;                  // 524,288
    float* sbuf     = lev[3] + 524288;          // 16,384
    float* pbuf     = sbuf + 16384;             // 16,384
    float* partials = pbuf + 16384;             // 131,072 (64 chunks x B x 1024)
    float* ctx      = partials + 131072;        // 2,048
    float* film     = ctx + 2048;               // 1,024
    unsigned short* h16   = (unsigned short*)(film + 1024);  // 4,194,304
    unsigned short* qkv16 = h16 + 4194304;      // 12,582,912 (stem-A aliases here)
    unsigned short* ov16  = qkv16 + 12582912;   // 4,194,304
    unsigned short* qw16  = ov16 + 4194304;     // 196,608
    unsigned short* ow16  = qw16 + 196608;      // 65,536
    unsigned short* sw16  = ow16 + 65536;       // 131,072

    // ---- weight + stem-A prep (bf16) ----
    f2b_kernel<<<(196608 + 255) / 256, 256, 0, stream>>>(qkv_w, qw16, 196608);
    f2b_kernel<<<(65536 + 255) / 256, 256, 0, stream>>>(out_w, ow16, 65536);
    stem_wprep<<<(131072 + 255) / 256, 256, 0, stream>>>(stem_w, sw16);
    unsigned short* stemA = qkv16;  // dead before qkv16 is first written
    stem_prep<<<(B_SZ * L_SEQ * 512) / 256, 256, 0, stream>>>(x, stemA);

    // ---- stem conv as bf16 GEMM -> h (fp32 + bf16) ----
    gemm_bf16<<<dim3(CH / 128, B_SZ * L_SEQ / 128), 256, 0, stream>>>(
        stemA, sw16, h32, h16, B_SZ * L_SEQ, CH, 512, stem_b);

    // ---- hierarchy levels ----
    for (int i = 0; i < NLEV; ++i) {
        const int l = L_SEQ >> i;
        const int M = B_SZ * l;
        gemm_bf16<<<dim3(768 / 128, M / 128), 256, 0, stream>>>(
            h16, qw16, nullptr, qkv16, M, 768, CH, nullptr);
        width_kernel<<<M / 4, 256, 0, stream>>>(h32, width_w, width_b, width);
        attn_kernel<<<M / 4, 256, 0, stream>>>(qkv16, width, ov16, l);
        gemm_bf16<<<dim3(CH / 128, M / 128), 256, 0, stream>>>(
            ov16, ow16, lev[i], nullptr, M, CH, CH, nullptr);
        if (i < NLEV - 1) {
            int total = (M / 2) * CH;
            downsample_kernel<<<(total + 255) / 256, 256, 0, stream>>>(
                lev[i], h32, h16, total);
        }
    }

    // ---- global attention + FiLM (fp32 tail) ----
    gattn_score_kernel<<<B_SZ * L_SEQ / 4, 256, 0, stream>>>(
        lev[0], lev[1], lev[2], lev[3], query, sbuf);
    softmax_L_kernel<<<B_SZ, 1024, 0, stream>>>(sbuf, pbuf);
    ctx_partial_kernel<<<dim3(64, B_SZ), 1024, 0, stream>>>(
        pbuf, lev[0], lev[1], lev[2], lev[3], partials);
    ctx_reduce_kernel<<<dim3(4, B_SZ), 256, 0, stream>>>(partials, ctx);
    film_kernel<<<128, 256, 0, stream>>>(ctx, film_w, film_b, film);
    final_kernel<<<(B_SZ * L_SEQ * CH) / 256, 256, 0, stream>>>(lev[0], film, out);
}

// Round 4
// 360.644 us; speedup vs baseline: 3.3294x; 1.1984x over previous
//
#include <hip/hip_runtime.h>
#include <math.h>

#define L_SEQ 8192
#define B_SZ  2
#define CH    256
#define NLEV  4

typedef __attribute__((ext_vector_type(8))) short bf16x8;
typedef __attribute__((ext_vector_type(4))) float f32x4;

static __device__ __forceinline__ float sigmoidf_(float x) {
    return 1.0f / (1.0f + expf(-x));
}

// bf16 (stored as ushort) <-> fp32 helpers. bf2f is exact; f2b is RNE.
static __device__ __forceinline__ float bf2f_(unsigned short u) {
    union { unsigned int ui; float f; } x;
    x.ui = ((unsigned int)u) << 16;
    return x.f;
}
static __device__ __forceinline__ unsigned short f2b_(float f) {
    union { float f; unsigned int u; } x;
    x.f = f;
    unsigned int lsb = (x.u >> 16) & 1u;
    unsigned int r = x.u + 0x7fffu + lsb;
    return (unsigned short)(r >> 16);
}

// ---------------------------------------------------------------------------
// MFMA bf16 GEMM (m97 structure): out[m,n] = sum_k A[m,k]*W[n,k] (+bias[n]).
// 128x128 tile, 4 waves, BK=32, global_load_lds width=16.
// ---------------------------------------------------------------------------
__global__ __launch_bounds__(256) void gemm_bf16(
    const unsigned short* __restrict__ A, const unsigned short* __restrict__ W,
    float* __restrict__ outF, unsigned short* __restrict__ outB,
    int M, int N, int Kd, const float* __restrict__ bias)
{
    __shared__ unsigned short As[128 * 32];
    __shared__ unsigned short Bs[128 * 32];
    const int tid  = threadIdx.x;
    const int wave = tid >> 6;
    const int lane = tid & 63;
    const int bm = blockIdx.y * 128;
    const int bn = blockIdx.x * 128;
    const int wm = (wave & 1) * 64;
    const int wn = (wave >> 1) * 64;

    const int srow = lane >> 2;
    const int scol = (lane & 3) * 8;

    f32x4 acc[4][4] = {};

    for (int k0 = 0; k0 < Kd; k0 += 32) {
        __syncthreads();
        #pragma unroll
        for (int c = 0; c < 2; ++c) {
            const int chunk = c * 4 + wave;
            const int row = chunk * 16 + srow;
            const unsigned short* ga = A + (size_t)(bm + row) * Kd + k0 + scol;
            const unsigned short* gw = W + (size_t)(bn + row) * Kd + k0 + scol;
            __builtin_amdgcn_global_load_lds(
                (const __attribute__((address_space(1))) void*)ga,
                (__attribute__((address_space(3))) void*)(As + chunk * 16 * 32),
                16, 0, 0);
            __builtin_amdgcn_global_load_lds(
                (const __attribute__((address_space(1))) void*)gw,
                (__attribute__((address_space(3))) void*)(Bs + chunk * 16 * 32),
                16, 0, 0);
        }
        __syncthreads();

        bf16x8 af[4], bf[4];
        const int fr = lane & 15;
        const int kk = (lane >> 4) * 8;
        #pragma unroll
        for (int i = 0; i < 4; ++i) {
            af[i] = *(const bf16x8*)(As + (wm + i * 16 + fr) * 32 + kk);
            bf[i] = *(const bf16x8*)(Bs + (wn + i * 16 + fr) * 32 + kk);
        }
        #pragma unroll
        for (int i = 0; i < 4; ++i)
            #pragma unroll
            for (int j = 0; j < 4; ++j)
                acc[i][j] = __builtin_amdgcn_mfma_f32_16x16x32_bf16(
                    af[i], bf[j], acc[i][j], 0, 0, 0);
    }

    const int cn = lane & 15;
    const int cr = (lane >> 4) * 4;
    #pragma unroll
    for (int i = 0; i < 4; ++i) {
        #pragma unroll
        for (int r = 0; r < 4; ++r) {
            const int m = bm + wm + i * 16 + cr + r;
            const size_t rowoff = (size_t)m * N;
            #pragma unroll
            for (int j = 0; j < 4; ++j) {
                const int n = bn + wn + j * 16 + cn;
                float v = acc[i][j][r];
                if (bias) v += bias[n];
                if (outF) outF[rowoff + n] = v;
                if (outB) outB[rowoff + n] = f2b_(v);
            }
        }
    }
}

// ---------------------------------------------------------------------------
// Prep kernels: fp32 -> bf16
// ---------------------------------------------------------------------------
__global__ void f2b_kernel(const float* __restrict__ in,
                           unsigned short* __restrict__ out, int n)
{
    int i = blockIdx.x * 256 + threadIdx.x;
    if (i < n) out[i] = f2b_(in[i]);
}

__global__ void stem_prep(const float* __restrict__ x,
                          unsigned short* __restrict__ As)
{
    size_t idx = (size_t)blockIdx.x * 256 + threadIdx.x;  // M*512
    int k = (int)(idx & 511);
    size_t m = idx >> 9;
    int t = (int)(m & (L_SEQ - 1));
    float v;
    if (k < 256) v = (t > 0) ? x[(m - 1) * CH + k] : 0.0f;
    else         v = x[m * CH + (k - 256)];
    As[idx] = f2b_(v);
}

__global__ void stem_wprep(const float* __restrict__ sw,
                           unsigned short* __restrict__ Ws)
{
    int idx = blockIdx.x * 256 + threadIdx.x;  // 256*512
    int k = idx & 511, n = idx >> 9;
    float v = (k < 256) ? sw[(size_t)n * 512 + k * 2]
                        : sw[(size_t)n * 512 + (k - 256) * 2 + 1];
    Ws[idx] = f2b_(v);
}

// ---------------------------------------------------------------------------
// width[row] = sigmoid(h[row]·ww + wb)*8 + 0.5   (one wave per row, fp32 h)
// ---------------------------------------------------------------------------
__global__ __launch_bounds__(256) void width_kernel(
    const float* __restrict__ h, const float* __restrict__ ww,
    const float* __restrict__ wb, float* __restrict__ width)
{
    const int lane = threadIdx.x & 63;
    const int row = blockIdx.x * 4 + (threadIdx.x >> 6);
    const float4 hv = *((const float4*)(h + (size_t)row * CH) + lane);
    const float4 wv = *((const float4*)ww + lane);
    float part = hv.x * wv.x + hv.y * wv.y + hv.z * wv.z + hv.w * wv.w;
    #pragma unroll
    for (int m = 1; m < 64; m <<= 1) part += __shfl_xor(part, m, 64);
    if (lane == 0) width[row] = sigmoidf_(part + wb[0]) * 8.0f + 0.5f;
}

// ---------------------------------------------------------------------------
// MFMA local attention. Block = 64 positions (4 waves x 16-row tiles).
// Phase 1: stage K rows [t0-8, t0+72) -> LDS [80][272] (pad 16 -> banks ok).
// Scores S(16x32) = Q*K^T via 16 mfma_16x16x32 per wave; softmax with band
// mask (w = c - i in [0,16]); +1 at center weight folds in the o+v residual.
// P -> LDS -> A-frag. Phase 2: stage V transposed Vt[256][88] (same buffer).
// PV: 16 single-K-step MFMAs -> bf16 stores.
// ---------------------------------------------------------------------------
__global__ __launch_bounds__(256) void attn_mfma_kernel(
    const unsigned short* __restrict__ qkv, const float* __restrict__ width,
    unsigned short* __restrict__ ov, int l)
{
    __shared__ unsigned short kv[22528];      // K [80][272] then Vt [256][88]
    __shared__ unsigned short pb[4 * 512];    // P per wave [16][32]

    const int tid  = threadIdx.x;
    const int wave = tid >> 6;
    const int lane = tid & 63;
    const int q    = lane >> 4;
    const int n    = lane & 15;

    const int blocks_per_seq = l >> 6;
    const int b  = blockIdx.x / blocks_per_seq;
    const int t0 = (blockIdx.x % blocks_per_seq) << 6;
    const size_t seqbase = (size_t)b * l;

    // ---- phase 1: stage K ----
    #pragma unroll
    for (int i = 0; i < 10; ++i) {
        int task = i * 256 + tid;
        int r = task >> 5, chunk = task & 31;
        int grow = t0 - 8 + r;
        bf16x8 val = {0, 0, 0, 0, 0, 0, 0, 0};
        if (grow >= 0 && grow < l)
            val = *(const bf16x8*)(qkv + (seqbase + grow) * 768 + 256 + chunk * 8);
        *(bf16x8*)(kv + r * 272 + chunk * 8) = val;
    }
    __syncthreads();

    const int row0 = t0 + wave * 16;  // first position of this wave's tile

    // Q A-fragments straight from global (row = row0+n, k-chunk = kk*32+q*8)
    bf16x8 qf[8];
    const unsigned short* qrow = qkv + (seqbase + row0 + n) * 768;
    #pragma unroll
    for (int kk = 0; kk < 8; ++kk)
        qf[kk] = *(const bf16x8*)(qrow + kk * 32 + q * 8);

    f32x4 accS[2] = {};
    #pragma unroll
    for (int kk = 0; kk < 8; ++kk) {
        #pragma unroll
        for (int h = 0; h < 2; ++h) {
            bf16x8 bk = *(const bf16x8*)(kv + (wave * 16 + h * 16 + n) * 272 +
                                         kk * 32 + q * 8);
            accS[h] = __builtin_amdgcn_mfma_f32_16x16x32_bf16(
                qf[kk], bk, accS[h], 0, 0, 0);
        }
    }

    // widths for this lane's 4 rows (i = q*4+r)
    float wd[4];
    #pragma unroll
    for (int r = 0; r < 4; ++r)
        wd[r] = width[seqbase + row0 + q * 4 + r];

    // mask + scale (C-layout: col c = h*16+n, row i = q*4+r)
    float s[2][4];
    #pragma unroll
    for (int h = 0; h < 2; ++h)
        #pragma unroll
        for (int r = 0; r < 4; ++r) {
            int ii = q * 4 + r;
            int c  = h * 16 + n;
            int w  = c - ii;
            float dist = fabsf((float)w - 8.0f);
            float sm = sigmoidf_((wd[r] - dist) * 5.0f);
            float v = accS[h][r] * 0.0625f - (1.0f - sm) * 10000.0f;
            s[h][r] = (w >= 0 && w <= 16) ? v : -3.0e38f;
        }

    // softmax over the row (16 lanes of the quad hold the 32 cols)
    float mx[4], sum[4];
    #pragma unroll
    for (int r = 0; r < 4; ++r) mx[r] = fmaxf(s[0][r], s[1][r]);
    #pragma unroll
    for (int m = 1; m < 16; m <<= 1)
        #pragma unroll
        for (int r = 0; r < 4; ++r) mx[r] = fmaxf(mx[r], __shfl_xor(mx[r], m, 64));
    float e[2][4];
    #pragma unroll
    for (int h = 0; h < 2; ++h)
        #pragma unroll
        for (int r = 0; r < 4; ++r) e[h][r] = expf(s[h][r] - mx[r]);
    #pragma unroll
    for (int r = 0; r < 4; ++r) sum[r] = e[0][r] + e[1][r];
    #pragma unroll
    for (int m = 1; m < 16; m <<= 1)
        #pragma unroll
        for (int r = 0; r < 4; ++r) sum[r] += __shfl_xor(sum[r], m, 64);

    // write P (bf16), folding the o+v residual: +1 at center col c == ii+8
    #pragma unroll
    for (int h = 0; h < 2; ++h)
        #pragma unroll
        for (int r = 0; r < 4; ++r) {
            int ii = q * 4 + r, c = h * 16 + n;
            float p = e[h][r] / sum[r];
            if (c == ii + 8) p += 1.0f;
            pb[wave * 512 + ii * 32 + c] = f2b_(p);
        }
    __syncthreads();  // all waves done reading K region

    // ---- phase 2: stage V transposed into kv as Vt[256][88] ----
    #pragma unroll
    for (int p5 = 0; p5 < 5; ++p5)
        #pragma unroll
        for (int cc = 0; cc < 2; ++cc) {
            int r = p5 * 16 + (tid & 15);
            int chunk = cc * 16 + (tid >> 4);
            int grow = t0 - 8 + r;
            bf16x8 val = {0, 0, 0, 0, 0, 0, 0, 0};
            if (grow >= 0 && grow < l)
                val = *(const bf16x8*)(qkv + (seqbase + grow) * 768 + 512 + chunk * 8);
            #pragma unroll
            for (int jj = 0; jj < 8; ++jj)
                kv[(chunk * 8 + jj) * 88 + r] = ((unsigned short*)&val)[jj];
        }
    __syncthreads();

    // ---- PV: A = P (A-layout: row = n, k = q*8..), B = Vt slices ----
    bf16x8 pf = *(const bf16x8*)(pb + wave * 512 + n * 32 + q * 8);
    const size_t obase = (seqbase + row0) * 256;
    #pragma unroll
    for (int chunk = 0; chunk < 16; ++chunk) {
        bf16x8 vf = *(const bf16x8*)(kv + (chunk * 16 + n) * 88 + wave * 16 + q * 8);
        f32x4 z = {};
        f32x4 o = __builtin_amdgcn_mfma_f32_16x16x32_bf16(pf, vf, z, 0, 0, 0);
        #pragma unroll
        for (int r = 0; r < 4; ++r)
            ov[obase + (size_t)(q * 4 + r) * 256 + chunk * 16 + n] = f2b_(o[r]);
    }
}

// ---------------------------------------------------------------------------
// Mean-pool pairs -> next level h (fp32 + bf16)
// ---------------------------------------------------------------------------
__global__ void downsample_kernel(const float* __restrict__ in,
                                  float* __restrict__ out32,
                                  unsigned short* __restrict__ out16, int total)
{
    int idx = blockIdx.x * 256 + threadIdx.x;
    if (idx >= total) return;
    int c = idx & (CH - 1);
    int r = idx >> 8;
    float v = 0.5f * (in[(size_t)(2 * r) * CH + c] + in[(size_t)(2 * r + 1) * CH + c]);
    out32[idx] = v;
    out16[idx] = f2b_(v);
}

// ---------------------------------------------------------------------------
// s[b,t] = sum_lev levels[lev][b, t>>lev, :]·query[lev*256:+256] (wave/(b,t))
// ---------------------------------------------------------------------------
__global__ __launch_bounds__(256) void gattn_score_kernel(
    const float* __restrict__ l0, const float* __restrict__ l1,
    const float* __restrict__ l2, const float* __restrict__ l3,
    const float* __restrict__ query, float* __restrict__ s)
{
    const int lane = threadIdx.x & 63;
    const int row = blockIdx.x * 4 + (threadIdx.x >> 6);
    const int b = row >> 13;
    const int t = row & (L_SEQ - 1);
    const float* levp[4] = {l0, l1, l2, l3};
    float part = 0.0f;
    #pragma unroll
    for (int lev = 0; lev < 4; ++lev) {
        const float* lp = levp[lev] + ((size_t)b * (L_SEQ >> lev) + (t >> lev)) * CH;
        float4 hv = *((const float4*)lp + lane);
        float4 qv = *((const float4*)(query + lev * CH) + lane);
        part += hv.x * qv.x + hv.y * qv.y + hv.z * qv.z + hv.w * qv.w;
    }
    #pragma unroll
    for (int m = 1; m < 64; m <<= 1) part += __shfl_xor(part, m, 64);
    if (lane == 0) s[row] = part;
}

// Softmax over L per batch. grid = B, block = 1024.
__global__ __launch_bounds__(1024) void softmax_L_kernel(
    const float* __restrict__ s, float* __restrict__ p)
{
    __shared__ float red[1024];
    const int b = blockIdx.x, tid = threadIdx.x;
    const float* sb = s + (size_t)b * L_SEQ;
    float mx = -1e30f;
    for (int i = tid; i < L_SEQ; i += 1024) mx = fmaxf(mx, sb[i]);
    red[tid] = mx; __syncthreads();
    for (int o = 512; o > 0; o >>= 1) {
        if (tid < o) red[tid] = fmaxf(red[tid], red[tid + o]);
        __syncthreads();
    }
    mx = red[0]; __syncthreads();
    float sum = 0.0f;
    for (int i = tid; i < L_SEQ; i += 1024) sum += expf(sb[i] - mx);
    red[tid] = sum; __syncthreads();
    for (int o = 512; o > 0; o >>= 1) {
        if (tid < o) red[tid] += red[tid + o];
        __syncthreads();
    }
    const float inv = 1.0f / red[0];
    for (int i = tid; i < L_SEQ; i += 1024) p[(size_t)b * L_SEQ + i] = expf(sb[i] - mx) * inv;
}

// Partial global-context: grid (64 chunks, B), block 1024 (d = lev*256+c).
__global__ __launch_bounds__(1024) void ctx_partial_kernel(
    const float* __restrict__ p,
    const float* __restrict__ l0, const float* __restrict__ l1,
    const float* __restrict__ l2, const float* __restrict__ l3,
    float* __restrict__ partials)
{
    const int d = threadIdx.x;
    const int lev = d >> 8, c = d & 255;
    const int chunk = blockIdx.x, b = blockIdx.y;
    const float* lp = (lev == 0) ? l0 : (lev == 1) ? l1 : (lev == 2) ? l2 : l3;
    lp += (size_t)b * (L_SEQ >> lev) * CH;
    const float* pb = p + (size_t)b * L_SEQ;
    float acc = 0.0f;
    const int t0 = chunk * 128;
    #pragma unroll 4
    for (int t = t0; t < t0 + 128; ++t)
        acc += pb[t] * lp[(size_t)(t >> lev) * CH + c];
    partials[(size_t)(b * 64 + chunk) * 1024 + d] = acc;
}

// grid (4, B), block 256: ctx[b*1024+d] = sum over 64 chunks
__global__ __launch_bounds__(256) void ctx_reduce_kernel(
    const float* __restrict__ partials, float* __restrict__ ctx)
{
    const int b = blockIdx.y;
    const int d = blockIdx.x * 256 + threadIdx.x;
    float acc = 0.0f;
    #pragma unroll
    for (int c = 0; c < 64; ++c) acc += partials[(size_t)(b * 64 + c) * 1024 + d];
    ctx[b * 1024 + d] = acc;
}

// film[b,j] = ctx[b,:]·fw[j,:] + fb[j]. One wave per j, both batches.
__global__ __launch_bounds__(256) void film_kernel(
    const float* __restrict__ ctx, const float* __restrict__ fw,
    const float* __restrict__ fb, float* __restrict__ film)
{
    const int lane = threadIdx.x & 63;
    const int j = blockIdx.x * 4 + (threadIdx.x >> 6);  // 0..511
    float acc0 = 0.0f, acc1 = 0.0f;
    #pragma unroll
    for (int r = 0; r < 4; ++r) {
        float4 w4 = *((const float4*)(fw + (size_t)j * 1024 + r * 256) + lane);
        float4 c0 = *((const float4*)(ctx + r * 256) + lane);
        float4 c1 = *((const float4*)(ctx + 1024 + r * 256) + lane);
        acc0 += w4.x * c0.x + w4.y * c0.y + w4.z * c0.z + w4.w * c0.w;
        acc1 += w4.x * c1.x + w4.y * c1.y + w4.z * c1.z + w4.w * c1.w;
    }
    #pragma unroll
    for (int m = 1; m < 64; m <<= 1) {
        acc0 += __shfl_xor(acc0, m, 64);
        acc1 += __shfl_xor(acc1, m, 64);
    }
    if (lane == 0) {
        float b = fb[j];
        film[j] = acc0 + b;
        film[512 + j] = acc1 + b;
    }
}

__global__ void final_kernel(const float* __restrict__ lev0,
                             const float* __restrict__ film,
                             float* __restrict__ out)
{
    size_t n = (size_t)blockIdx.x * 256 + threadIdx.x;
    int c = (int)(n & (CH - 1));
    int b = (int)(n >> 21);  // L*C = 2^21
    float s = film[b * 512 + c];
    float bi = film[b * 512 + 256 + c];
    out[n] = lev0[n] * (1.0f + s) + bi;
}

extern "C" void kernel_launch(void* const* d_in, const int* in_sizes, int n_in,
                              void* d_out, int out_size, void* d_ws, size_t ws_size,
                              hipStream_t stream) {
    const float* x       = (const float*)d_in[0];
    const float* stem_w  = (const float*)d_in[1];
    const float* stem_b  = (const float*)d_in[2];
    const float* qkv_w   = (const float*)d_in[3];
    const float* width_w = (const float*)d_in[4];
    const float* width_b = (const float*)d_in[5];
    const float* out_w   = (const float*)d_in[6];
    const float* query   = (const float*)d_in[7];
    const float* film_w  = (const float*)d_in[8];
    const float* film_b  = (const float*)d_in[9];
    float* out = (float*)d_out;
    float* ws  = (float*)d_ws;

    // ---- workspace layout (fp32 region then bf16 region) ----
    float* h32      = ws;                       // 4,194,304
    float* width    = h32 + 4194304;            // 16,384
    float* lev[4];
    lev[0] = width + 16384;                     // 4,194,304
    lev[1] = lev[0] + 4194304;                  // 2,097,152
    lev[2] = lev[1] + 2097152;                  // 1,048,576
    lev[3] = lev[2] + 1048576;                  // 524,288
    float* sbuf     = lev[3] + 524288;          // 16,384
    float* pbuf     = sbuf + 16384;             // 16,384
    float* partials = pbuf + 16384;             // 131,072
    float* ctx      = partials + 131072;        // 2,048
    float* film     = ctx + 2048;               // 1,024
    unsigned short* h16   = (unsigned short*)(film + 1024);  // 4,194,304
    unsigned short* qkv16 = h16 + 4194304;      // 12,582,912 (stem-A aliases here)
    unsigned short* ov16  = qkv16 + 12582912;   // 4,194,304
    unsigned short* qw16  = ov16 + 4194304;     // 196,608
    unsigned short* ow16  = qw16 + 196608;      // 65,536
    unsigned short* sw16  = ow16 + 65536;       // 131,072

    // ---- weight + stem-A prep (bf16) ----
    f2b_kernel<<<(196608 + 255) / 256, 256, 0, stream>>>(qkv_w, qw16, 196608);
    f2b_kernel<<<(65536 + 255) / 256, 256, 0, stream>>>(out_w, ow16, 65536);
    stem_wprep<<<(131072 + 255) / 256, 256, 0, stream>>>(stem_w, sw16);
    unsigned short* stemA = qkv16;  // dead before qkv16 is first written
    stem_prep<<<(B_SZ * L_SEQ * 512) / 256, 256, 0, stream>>>(x, stemA);

    // ---- stem conv as bf16 GEMM -> h (fp32 + bf16) ----
    gemm_bf16<<<dim3(CH / 128, B_SZ * L_SEQ / 128), 256, 0, stream>>>(
        stemA, sw16, h32, h16, B_SZ * L_SEQ, CH, 512, stem_b);

    // ---- hierarchy levels ----
    for (int i = 0; i < NLEV; ++i) {
        const int l = L_SEQ >> i;
        const int M = B_SZ * l;
        gemm_bf16<<<dim3(768 / 128, M / 128), 256, 0, stream>>>(
            h16, qw16, nullptr, qkv16, M, 768, CH, nullptr);
        width_kernel<<<M / 4, 256, 0, stream>>>(h32, width_w, width_b, width);
        attn_mfma_kernel<<<M / 64, 256, 0, stream>>>(qkv16, width, ov16, l);
        gemm_bf16<<<dim3(CH / 128, M / 128), 256, 0, stream>>>(
            ov16, ow16, lev[i], nullptr, M, CH, CH, nullptr);
        if (i < NLEV - 1) {
            int total = (M / 2) * CH;
            downsample_kernel<<<(total + 255) / 256, 256, 0, stream>>>(
                lev[i], h32, h16, total);
        }
    }

    // ---- global attention + FiLM (fp32 tail) ----
    gattn_score_kernel<<<B_SZ * L_SEQ / 4, 256, 0, stream>>>(
        lev[0], lev[1], lev[2], lev[3], query, sbuf);
    softmax_L_kernel<<<B_SZ, 1024, 0, stream>>>(sbuf, pbuf);
    ctx_partial_kernel<<<dim3(64, B_SZ), 1024, 0, stream>>>(
        pbuf, lev[0], lev[1], lev[2], lev[3], partials);
    ctx_reduce_kernel<<<dim3(4, B_SZ), 256, 0, stream>>>(partials, ctx);
    film_kernel<<<128, 256, 0, stream>>>(ctx, film_w, film_b, film);
    final_kernel<<<(B_SZ * L_SEQ * CH) / 256, 256, 0, stream>>>(lev[0], film, out);
}

// Round 5
// 296.511 us; speedup vs baseline: 4.0495x; 1.2163x over previous
//
#include <hip/hip_runtime.h>
#include <math.h>

#define L_SEQ 8192
#define B_SZ  2
#define CH    256
#define NLEV  4

typedef __attribute__((ext_vector_type(8))) short bf16x8;
typedef __attribute__((ext_vector_type(4))) float f32x4;

static __device__ __forceinline__ float sigmoidf_(float x) {
    return 1.0f / (1.0f + expf(-x));
}

// bf16 (stored as ushort) <-> fp32 helpers. bf2f is exact; f2b is RNE.
static __device__ __forceinline__ float bf2f_(unsigned short u) {
    union { unsigned int ui; float f; } x;
    x.ui = ((unsigned int)u) << 16;
    return x.f;
}
static __device__ __forceinline__ unsigned short f2b_(float f) {
    union { float f; unsigned int u; } x;
    x.f = f;
    unsigned int lsb = (x.u >> 16) & 1u;
    unsigned int r = x.u + 0x7fffu + lsb;
    return (unsigned short)(r >> 16);
}
static __device__ __forceinline__ float4 ldb4_(const unsigned short* p) {
    ushort4 u = *(const ushort4*)p;
    return make_float4(bf2f_(u.x), bf2f_(u.y), bf2f_(u.z), bf2f_(u.w));
}

// ---------------------------------------------------------------------------
// Fused fp32->bf16 prep: guard row (zeros) + x16 + qkv_w + out_w + stem_w.
// Grid covers exactly 256 + 4194304 + 196608 + 65536 + 131072 elements.
// ---------------------------------------------------------------------------
__global__ void prep_kernel(const float* __restrict__ x,
                            const float* __restrict__ qkv_w,
                            const float* __restrict__ out_w,
                            const float* __restrict__ stem_w,
                            unsigned short* __restrict__ x16g,
                            unsigned short* __restrict__ qw16,
                            unsigned short* __restrict__ ow16,
                            unsigned short* __restrict__ sw16)
{
    int i = blockIdx.x * 256 + threadIdx.x;
    if (i < 256) { x16g[i] = 0; return; }           // guard row of zeros
    i -= 256;
    if (i < 4194304) { x16g[256 + i] = f2b_(x[i]); return; }
    i -= 4194304;
    if (i < 196608) { qw16[i] = f2b_(qkv_w[i]); return; }
    i -= 196608;
    if (i < 65536) { ow16[i] = f2b_(out_w[i]); return; }
    i -= 65536;
    {   // stem W: (256,512); k<256 -> tap0, else tap1
        int k = i & 511, n = i >> 9;
        float v = (k < 256) ? stem_w[(size_t)n * 512 + k * 2]
                            : stem_w[(size_t)n * 512 + (k - 256) * 2 + 1];
        sw16[i] = f2b_(v);
    }
}

// ---------------------------------------------------------------------------
// Stem conv as MFMA GEMM, staging A directly from x16 (guard row at offset 0,
// row m data at x16g + (m+1)*256). Virtual A row m: [x[m-1] | x[m]] with
// zeros at t==0. M=16384, N=256, Kd=512. Writes h16 (bias added).
// ---------------------------------------------------------------------------
__global__ __launch_bounds__(256) void stem_gemm_bf16(
    const unsigned short* __restrict__ x16g, const unsigned short* __restrict__ W,
    unsigned short* __restrict__ outB, const float* __restrict__ bias)
{
    __shared__ unsigned short As[128 * 32];
    __shared__ unsigned short Bs[128 * 32];
    const int tid  = threadIdx.x;
    const int wave = tid >> 6;
    const int lane = tid & 63;
    const int bm = blockIdx.y * 128;
    const int bn = blockIdx.x * 128;
    const int wm = (wave & 1) * 64;
    const int wn = (wave >> 1) * 64;
    const int srow = lane >> 2;
    const int scol = (lane & 3) * 8;

    f32x4 acc[4][4] = {};

    for (int k0 = 0; k0 < 512; k0 += 32) {
        __syncthreads();
        #pragma unroll
        for (int c = 0; c < 2; ++c) {
            const int chunk = c * 4 + wave;
            const int row = bm + chunk * 16 + srow;
            const int t = row & (L_SEQ - 1);
            const unsigned short* ga;
            if (k0 < 256)  // prev-row half: guard (zeros) when t==0
                ga = x16g + (t > 0 ? (size_t)row * 256 : 0) + k0 + scol;
            else           // cur-row half
                ga = x16g + ((size_t)row + 1) * 256 + (k0 - 256) + scol;
            const unsigned short* gw = W + (size_t)(bn + chunk * 16 + srow) * 512 + k0 + scol;
            __builtin_amdgcn_global_load_lds(
                (const __attribute__((address_space(1))) void*)ga,
                (__attribute__((address_space(3))) void*)(As + chunk * 16 * 32),
                16, 0, 0);
            __builtin_amdgcn_global_load_lds(
                (const __attribute__((address_space(1))) void*)gw,
                (__attribute__((address_space(3))) void*)(Bs + chunk * 16 * 32),
                16, 0, 0);
        }
        __syncthreads();

        bf16x8 af[4], bf[4];
        const int fr = lane & 15;
        const int kk = (lane >> 4) * 8;
        #pragma unroll
        for (int i = 0; i < 4; ++i) {
            af[i] = *(const bf16x8*)(As + (wm + i * 16 + fr) * 32 + kk);
            bf[i] = *(const bf16x8*)(Bs + (wn + i * 16 + fr) * 32 + kk);
        }
        #pragma unroll
        for (int i = 0; i < 4; ++i)
            #pragma unroll
            for (int j = 0; j < 4; ++j)
                acc[i][j] = __builtin_amdgcn_mfma_f32_16x16x32_bf16(
                    af[i], bf[j], acc[i][j], 0, 0, 0);
    }

    const int cn = lane & 15;
    const int cr = (lane >> 4) * 4;
    #pragma unroll
    for (int i = 0; i < 4; ++i)
        #pragma unroll
        for (int r = 0; r < 4; ++r) {
            const int m = bm + wm + i * 16 + cr + r;
            #pragma unroll
            for (int j = 0; j < 4; ++j) {
                const int n = bn + wn + j * 16 + cn;
                outB[(size_t)m * CH + n] = f2b_(acc[i][j][r] + bias[n]);
            }
        }
}

// ---------------------------------------------------------------------------
// Generic MFMA bf16 GEMM (m97 structure): out = A @ W^T, bf16 out.
// ---------------------------------------------------------------------------
__global__ __launch_bounds__(256) void gemm_bf16(
    const unsigned short* __restrict__ A, const unsigned short* __restrict__ W,
    unsigned short* __restrict__ outB, int M, int N, int Kd)
{
    __shared__ unsigned short As[128 * 32];
    __shared__ unsigned short Bs[128 * 32];
    const int tid  = threadIdx.x;
    const int wave = tid >> 6;
    const int lane = tid & 63;
    const int bm = blockIdx.y * 128;
    const int bn = blockIdx.x * 128;
    const int wm = (wave & 1) * 64;
    const int wn = (wave >> 1) * 64;
    const int srow = lane >> 2;
    const int scol = (lane & 3) * 8;

    f32x4 acc[4][4] = {};

    for (int k0 = 0; k0 < Kd; k0 += 32) {
        __syncthreads();
        #pragma unroll
        for (int c = 0; c < 2; ++c) {
            const int chunk = c * 4 + wave;
            const int row = chunk * 16 + srow;
            const unsigned short* ga = A + (size_t)(bm + row) * Kd + k0 + scol;
            const unsigned short* gw = W + (size_t)(bn + row) * Kd + k0 + scol;
            __builtin_amdgcn_global_load_lds(
                (const __attribute__((address_space(1))) void*)ga,
                (__attribute__((address_space(3))) void*)(As + chunk * 16 * 32),
                16, 0, 0);
            __builtin_amdgcn_global_load_lds(
                (const __attribute__((address_space(1))) void*)gw,
                (__attribute__((address_space(3))) void*)(Bs + chunk * 16 * 32),
                16, 0, 0);
        }
        __syncthreads();

        bf16x8 af[4], bf[4];
        const int fr = lane & 15;
        const int kk = (lane >> 4) * 8;
        #pragma unroll
        for (int i = 0; i < 4; ++i) {
            af[i] = *(const bf16x8*)(As + (wm + i * 16 + fr) * 32 + kk);
            bf[i] = *(const bf16x8*)(Bs + (wn + i * 16 + fr) * 32 + kk);
        }
        #pragma unroll
        for (int i = 0; i < 4; ++i)
            #pragma unroll
            for (int j = 0; j < 4; ++j)
                acc[i][j] = __builtin_amdgcn_mfma_f32_16x16x32_bf16(
                    af[i], bf[j], acc[i][j], 0, 0, 0);
    }

    const int cn = lane & 15;
    const int cr = (lane >> 4) * 4;
    #pragma unroll
    for (int i = 0; i < 4; ++i)
        #pragma unroll
        for (int r = 0; r < 4; ++r) {
            const int m = bm + wm + i * 16 + cr + r;
            const size_t rowoff = (size_t)m * N;
            #pragma unroll
            for (int j = 0; j < 4; ++j)
                outB[rowoff + bn + wn + j * 16 + cn] = f2b_(acc[i][j][r]);
        }
}

// ---------------------------------------------------------------------------
// Out-proj GEMM (N=256) with fused epilogue: bf16 lev16 (always), fp32 lev0
// (optional), and pair-mean downsample -> next level h16 (optional). Each
// lane holds 4 consecutive rows (even base), so the pair-mean is in-register.
// ---------------------------------------------------------------------------
__global__ __launch_bounds__(256) void gemm_out_bf16(
    const unsigned short* __restrict__ A, const unsigned short* __restrict__ W,
    float* __restrict__ outF, unsigned short* __restrict__ outB,
    unsigned short* __restrict__ dsB, int M)
{
    __shared__ unsigned short As[128 * 32];
    __shared__ unsigned short Bs[128 * 32];
    const int tid  = threadIdx.x;
    const int wave = tid >> 6;
    const int lane = tid & 63;
    const int bm = blockIdx.y * 128;
    const int bn = blockIdx.x * 128;
    const int wm = (wave & 1) * 64;
    const int wn = (wave >> 1) * 64;
    const int srow = lane >> 2;
    const int scol = (lane & 3) * 8;

    f32x4 acc[4][4] = {};

    for (int k0 = 0; k0 < 256; k0 += 32) {
        __syncthreads();
        #pragma unroll
        for (int c = 0; c < 2; ++c) {
            const int chunk = c * 4 + wave;
            const int row = chunk * 16 + srow;
            const unsigned short* ga = A + (size_t)(bm + row) * 256 + k0 + scol;
            const unsigned short* gw = W + (size_t)(bn + row) * 256 + k0 + scol;
            __builtin_amdgcn_global_load_lds(
                (const __attribute__((address_space(1))) void*)ga,
                (__attribute__((address_space(3))) void*)(As + chunk * 16 * 32),
                16, 0, 0);
            __builtin_amdgcn_global_load_lds(
                (const __attribute__((address_space(1))) void*)gw,
                (__attribute__((address_space(3))) void*)(Bs + chunk * 16 * 32),
                16, 0, 0);
        }
        __syncthreads();

        bf16x8 af[4], bf[4];
        const int fr = lane & 15;
        const int kk = (lane >> 4) * 8;
        #pragma unroll
        for (int i = 0; i < 4; ++i) {
            af[i] = *(const bf16x8*)(As + (wm + i * 16 + fr) * 32 + kk);
            bf[i] = *(const bf16x8*)(Bs + (wn + i * 16 + fr) * 32 + kk);
        }
        #pragma unroll
        for (int i = 0; i < 4; ++i)
            #pragma unroll
            for (int j = 0; j < 4; ++j)
                acc[i][j] = __builtin_amdgcn_mfma_f32_16x16x32_bf16(
                    af[i], bf[j], acc[i][j], 0, 0, 0);
    }

    const int cn = lane & 15;
    const int cr = (lane >> 4) * 4;   // even
    #pragma unroll
    for (int i = 0; i < 4; ++i) {
        const int base = bm + wm + i * 16 + cr;
        #pragma unroll
        for (int j = 0; j < 4; ++j) {
            const int col = bn + wn + j * 16 + cn;
            float v0 = acc[i][j][0], v1 = acc[i][j][1];
            float v2 = acc[i][j][2], v3 = acc[i][j][3];
            outB[(size_t)(base + 0) * CH + col] = f2b_(v0);
            outB[(size_t)(base + 1) * CH + col] = f2b_(v1);
            outB[(size_t)(base + 2) * CH + col] = f2b_(v2);
            outB[(size_t)(base + 3) * CH + col] = f2b_(v3);
            if (outF) {
                outF[(size_t)(base + 0) * CH + col] = v0;
                outF[(size_t)(base + 1) * CH + col] = v1;
                outF[(size_t)(base + 2) * CH + col] = v2;
                outF[(size_t)(base + 3) * CH + col] = v3;
            }
            if (dsB) {
                dsB[(size_t)(base >> 1) * CH + col]       = f2b_(0.5f * (v0 + v1));
                dsB[(size_t)((base >> 1) + 1) * CH + col] = f2b_(0.5f * (v2 + v3));
            }
        }
    }
}

// ---------------------------------------------------------------------------
// MFMA local attention with fused width head. Block = 64 positions
// (4 waves x 16 rows). width = sigmoid(h·ww+wb)*8+0.5 computed in-wave.
// ---------------------------------------------------------------------------
__global__ __launch_bounds__(256) void attn_mfma_kernel(
    const unsigned short* __restrict__ qkv, const unsigned short* __restrict__ h16,
    const float* __restrict__ ww, const float* __restrict__ wbp,
    unsigned short* __restrict__ ov, int l)
{
    __shared__ unsigned short kv[22528];      // K [80][272] then Vt [256][88]
    __shared__ unsigned short pb[4 * 512];    // P per wave [16][32]

    const int tid  = threadIdx.x;
    const int wave = tid >> 6;
    const int lane = tid & 63;
    const int q    = lane >> 4;
    const int n    = lane & 15;

    const int blocks_per_seq = l >> 6;
    const int b  = blockIdx.x / blocks_per_seq;
    const int t0 = (blockIdx.x % blocks_per_seq) << 6;
    const size_t seqbase = (size_t)b * l;
    const int row0 = t0 + wave * 16;

    // ---- phase 1: stage K ----
    #pragma unroll
    for (int i = 0; i < 10; ++i) {
        int task = i * 256 + tid;
        int r = task >> 5, chunk = task & 31;
        int grow = t0 - 8 + r;
        bf16x8 val = {0, 0, 0, 0, 0, 0, 0, 0};
        if (grow >= 0 && grow < l)
            val = *(const bf16x8*)(qkv + (seqbase + grow) * 768 + 256 + chunk * 8);
        *(bf16x8*)(kv + r * 272 + chunk * 8) = val;
    }

    // ---- fused width: lane (q,n) accumulates cols [q*64, q*64+64) of row n ----
    float wdot = 0.0f;
    {
        const unsigned short* hrow = h16 + (seqbase + row0 + n) * 256 + q * 64;
        #pragma unroll
        for (int jj = 0; jj < 8; ++jj) {
            bf16x8 hv = *(const bf16x8*)(hrow + jj * 8);
            float4 wa = *((const float4*)(ww + q * 64 + jj * 8));
            float4 wc = *((const float4*)(ww + q * 64 + jj * 8 + 4));
            wdot += bf2f_(((unsigned short*)&hv)[0]) * wa.x
                  + bf2f_(((unsigned short*)&hv)[1]) * wa.y
                  + bf2f_(((unsigned short*)&hv)[2]) * wa.z
                  + bf2f_(((unsigned short*)&hv)[3]) * wa.w
                  + bf2f_(((unsigned short*)&hv)[4]) * wc.x
                  + bf2f_(((unsigned short*)&hv)[5]) * wc.y
                  + bf2f_(((unsigned short*)&hv)[6]) * wc.z
                  + bf2f_(((unsigned short*)&hv)[7]) * wc.w;
        }
    }
    wdot += __shfl_xor(wdot, 16, 64);
    wdot += __shfl_xor(wdot, 32, 64);
    const float w_n = sigmoidf_(wdot + wbp[0]) * 8.0f + 0.5f;  // width of row n

    __syncthreads();

    // Q A-fragments straight from global
    bf16x8 qf[8];
    const unsigned short* qrow = qkv + (seqbase + row0 + n) * 768;
    #pragma unroll
    for (int kk = 0; kk < 8; ++kk)
        qf[kk] = *(const bf16x8*)(qrow + kk * 32 + q * 8);

    f32x4 accS[2] = {};
    #pragma unroll
    for (int kk = 0; kk < 8; ++kk) {
        #pragma unroll
        for (int h = 0; h < 2; ++h) {
            bf16x8 bk = *(const bf16x8*)(kv + (wave * 16 + h * 16 + n) * 272 +
                                         kk * 32 + q * 8);
            accS[h] = __builtin_amdgcn_mfma_f32_16x16x32_bf16(
                qf[kk], bk, accS[h], 0, 0, 0);
        }
    }

    // widths for this lane's 4 C-layout rows (i = q*4+r), pulled via shfl
    float wd[4];
    #pragma unroll
    for (int r = 0; r < 4; ++r) wd[r] = __shfl(w_n, q * 4 + r, 64);

    // mask + scale (C-layout: col c = h*16+n, row i = q*4+r)
    float s[2][4];
    #pragma unroll
    for (int h = 0; h < 2; ++h)
        #pragma unroll
        for (int r = 0; r < 4; ++r) {
            int ii = q * 4 + r;
            int c  = h * 16 + n;
            int w  = c - ii;
            float dist = fabsf((float)w - 8.0f);
            float sm = sigmoidf_((wd[r] - dist) * 5.0f);
            float v = accS[h][r] * 0.0625f - (1.0f - sm) * 10000.0f;
            s[h][r] = (w >= 0 && w <= 16) ? v : -3.0e38f;
        }

    // softmax over the row (16 lanes of the quad hold the 32 cols)
    float mx[4], sum[4];
    #pragma unroll
    for (int r = 0; r < 4; ++r) mx[r] = fmaxf(s[0][r], s[1][r]);
    #pragma unroll
    for (int m = 1; m < 16; m <<= 1)
        #pragma unroll
        for (int r = 0; r < 4; ++r) mx[r] = fmaxf(mx[r], __shfl_xor(mx[r], m, 64));
    float e[2][4];
    #pragma unroll
    for (int h = 0; h < 2; ++h)
        #pragma unroll
        for (int r = 0; r < 4; ++r) e[h][r] = expf(s[h][r] - mx[r]);
    #pragma unroll
    for (int r = 0; r < 4; ++r) sum[r] = e[0][r] + e[1][r];
    #pragma unroll
    for (int m = 1; m < 16; m <<= 1)
        #pragma unroll
        for (int r = 0; r < 4; ++r) sum[r] += __shfl_xor(sum[r], m, 64);

    // write P (bf16), folding the o+v residual: +1 at center col c == ii+8
    #pragma unroll
    for (int h = 0; h < 2; ++h)
        #pragma unroll
        for (int r = 0; r < 4; ++r) {
            int ii = q * 4 + r, c = h * 16 + n;
            float p = e[h][r] / sum[r];
            if (c == ii + 8) p += 1.0f;
            pb[wave * 512 + ii * 32 + c] = f2b_(p);
        }
    __syncthreads();  // all waves done reading K region

    // ---- phase 2: stage V transposed into kv as Vt[256][88] ----
    #pragma unroll
    for (int p5 = 0; p5 < 5; ++p5)
        #pragma unroll
        for (int cc = 0; cc < 2; ++cc) {
            int r = p5 * 16 + (tid & 15);
            int chunk = cc * 16 + (tid >> 4);
            int grow = t0 - 8 + r;
            bf16x8 val = {0, 0, 0, 0, 0, 0, 0, 0};
            if (grow >= 0 && grow < l)
                val = *(const bf16x8*)(qkv + (seqbase + grow) * 768 + 512 + chunk * 8);
            #pragma unroll
            for (int jj = 0; jj < 8; ++jj)
                kv[(chunk * 8 + jj) * 88 + r] = ((unsigned short*)&val)[jj];
        }
    __syncthreads();

    // ---- PV: A = P (A-layout), B = Vt slices ----
    bf16x8 pf = *(const bf16x8*)(pb + wave * 512 + n * 32 + q * 8);
    const size_t obase = (seqbase + row0) * 256;
    #pragma unroll
    for (int chunk = 0; chunk < 16; ++chunk) {
        bf16x8 vf = *(const bf16x8*)(kv + (chunk * 16 + n) * 88 + wave * 16 + q * 8);
        f32x4 z = {};
        f32x4 o = __builtin_amdgcn_mfma_f32_16x16x32_bf16(pf, vf, z, 0, 0, 0);
        #pragma unroll
        for (int r = 0; r < 4; ++r)
            ov[obase + (size_t)(q * 4 + r) * 256 + chunk * 16 + n] = f2b_(o[r]);
    }
}

// ---------------------------------------------------------------------------
// s[b,t] = sum_lev lev16[lev][b, t>>lev, :]·query[lev*256:+256] (wave/(b,t))
// ---------------------------------------------------------------------------
__global__ __launch_bounds__(256) void gattn_score_kernel(
    const unsigned short* __restrict__ l0, const unsigned short* __restrict__ l1,
    const unsigned short* __restrict__ l2, const unsigned short* __restrict__ l3,
    const float* __restrict__ query, float* __restrict__ s)
{
    const int lane = threadIdx.x & 63;
    const int row = blockIdx.x * 4 + (threadIdx.x >> 6);
    const int b = row >> 13;
    const int t = row & (L_SEQ - 1);
    const unsigned short* levp[4] = {l0, l1, l2, l3};
    float part = 0.0f;
    #pragma unroll
    for (int lev = 0; lev < 4; ++lev) {
        const unsigned short* lp = levp[lev] +
            ((size_t)b * (L_SEQ >> lev) + (t >> lev)) * CH + lane * 4;
        float4 hv = ldb4_(lp);
        float4 qv = *((const float4*)(query + lev * CH) + lane);
        part += hv.x * qv.x + hv.y * qv.y + hv.z * qv.z + hv.w * qv.w;
    }
    #pragma unroll
    for (int m = 1; m < 64; m <<= 1) part += __shfl_xor(part, m, 64);
    if (lane == 0) s[row] = part;
}

// Softmax over L per batch. grid = B, block = 1024.
__global__ __launch_bounds__(1024) void softmax_L_kernel(
    const float* __restrict__ s, float* __restrict__ p)
{
    __shared__ float red[1024];
    const int b = blockIdx.x, tid = threadIdx.x;
    const float* sb = s + (size_t)b * L_SEQ;
    float mx = -1e30f;
    for (int i = tid; i < L_SEQ; i += 1024) mx = fmaxf(mx, sb[i]);
    red[tid] = mx; __syncthreads();
    for (int o = 512; o > 0; o >>= 1) {
        if (tid < o) red[tid] = fmaxf(red[tid], red[tid + o]);
        __syncthreads();
    }
    mx = red[0]; __syncthreads();
    float sum = 0.0f;
    for (int i = tid; i < L_SEQ; i += 1024) sum += expf(sb[i] - mx);
    red[tid] = sum; __syncthreads();
    for (int o = 512; o > 0; o >>= 1) {
        if (tid < o) red[tid] += red[tid + o];
        __syncthreads();
    }
    const float inv = 1.0f / red[0];
    for (int i = tid; i < L_SEQ; i += 1024) p[(size_t)b * L_SEQ + i] = expf(sb[i] - mx) * inv;
}

// Partial global-context over bf16 levels: grid (64 chunks, B), block 1024.
__global__ __launch_bounds__(1024) void ctx_partial_kernel(
    const float* __restrict__ p,
    const unsigned short* __restrict__ l0, const unsigned short* __restrict__ l1,
    const unsigned short* __restrict__ l2, const unsigned short* __restrict__ l3,
    float* __restrict__ partials)
{
    const int d = threadIdx.x;
    const int lev = d >> 8, c = d & 255;
    const int chunk = blockIdx.x, b = blockIdx.y;
    const unsigned short* lp = (lev == 0) ? l0 : (lev == 1) ? l1 : (lev == 2) ? l2 : l3;
    lp += (size_t)b * (L_SEQ >> lev) * CH;
    const float* pbv = p + (size_t)b * L_SEQ;
    float acc = 0.0f;
    const int t0 = chunk * 128;
    #pragma unroll 4
    for (int t = t0; t < t0 + 128; ++t)
        acc += pbv[t] * bf2f_(lp[(size_t)(t >> lev) * CH + c]);
    partials[(size_t)(b * 64 + chunk) * 1024 + d] = acc;
}

// grid (4, B), block 256: ctx[b*1024+d] = sum over 64 chunks
__global__ __launch_bounds__(256) void ctx_reduce_kernel(
    const float* __restrict__ partials, float* __restrict__ ctx)
{
    const int b = blockIdx.y;
    const int d = blockIdx.x * 256 + threadIdx.x;
    float acc = 0.0f;
    #pragma unroll
    for (int c = 0; c < 64; ++c) acc += partials[(size_t)(b * 64 + c) * 1024 + d];
    ctx[b * 1024 + d] = acc;
}

// film[b,j] = ctx[b,:]·fw[j,:] + fb[j]. One wave per j, both batches.
__global__ __launch_bounds__(256) void film_kernel(
    const float* __restrict__ ctx, const float* __restrict__ fw,
    const float* __restrict__ fb, float* __restrict__ film)
{
    const int lane = threadIdx.x & 63;
    const int j = blockIdx.x * 4 + (threadIdx.x >> 6);  // 0..511
    float acc0 = 0.0f, acc1 = 0.0f;
    #pragma unroll
    for (int r = 0; r < 4; ++r) {
        float4 w4 = *((const float4*)(fw + (size_t)j * 1024 + r * 256) + lane);
        float4 c0 = *((const float4*)(ctx + r * 256) + lane);
        float4 c1 = *((const float4*)(ctx + 1024 + r * 256) + lane);
        acc0 += w4.x * c0.x + w4.y * c0.y + w4.z * c0.z + w4.w * c0.w;
        acc1 += w4.x * c1.x + w4.y * c1.y + w4.z * c1.z + w4.w * c1.w;
    }
    #pragma unroll
    for (int m = 1; m < 64; m <<= 1) {
        acc0 += __shfl_xor(acc0, m, 64);
        acc1 += __shfl_xor(acc1, m, 64);
    }
    if (lane == 0) {
        float b = fb[j];
        film[j] = acc0 + b;
        film[512 + j] = acc1 + b;
    }
}

__global__ void final_kernel(const float* __restrict__ lev0,
                             const float* __restrict__ film,
                             float* __restrict__ out)
{
    size_t n = (size_t)blockIdx.x * 256 + threadIdx.x;
    int c = (int)(n & (CH - 1));
    int b = (int)(n >> 21);  // L*C = 2^21
    float s = film[b * 512 + c];
    float bi = film[b * 512 + 256 + c];
    out[n] = lev0[n] * (1.0f + s) + bi;
}

extern "C" void kernel_launch(void* const* d_in, const int* in_sizes, int n_in,
                              void* d_out, int out_size, void* d_ws, size_t ws_size,
                              hipStream_t stream) {
    const float* x       = (const float*)d_in[0];
    const float* stem_w  = (const float*)d_in[1];
    const float* stem_b  = (const float*)d_in[2];
    const float* qkv_w   = (const float*)d_in[3];
    const float* width_w = (const float*)d_in[4];
    const float* width_b = (const float*)d_in[5];
    const float* out_w   = (const float*)d_in[6];
    const float* query   = (const float*)d_in[7];
    const float* film_w  = (const float*)d_in[8];
    const float* film_b  = (const float*)d_in[9];
    float* out = (float*)d_out;
    float* ws  = (float*)d_ws;

    // ---- workspace layout ----
    float* lev0     = ws;                       // 4,194,304 fp32
    float* sbuf     = lev0 + 4194304;           // 16,384
    float* pbuf     = sbuf + 16384;             // 16,384
    float* partials = pbuf + 16384;             // 131,072
    float* ctx      = partials + 131072;        // 2,048
    float* film     = ctx + 2048;               // 1,024
    unsigned short* x16g  = (unsigned short*)(film + 1024);  // 256 guard + 4,194,304
    unsigned short* h16_0 = x16g + 4194560;     // 4,194,304
    unsigned short* h16_1 = h16_0 + 4194304;    // 2,097,152
    unsigned short* h16_2 = h16_1 + 2097152;    // 1,048,576
    unsigned short* h16_3 = h16_2 + 1048576;    //   524,288
    unsigned short* qkv16 = h16_3 + 524288;     // 12,582,912
    unsigned short* ov16  = qkv16 + 12582912;   // 4,194,304
    unsigned short* l16_0 = ov16 + 4194304;     // 4,194,304
    unsigned short* l16_1 = l16_0 + 4194304;    // 2,097,152
    unsigned short* l16_2 = l16_1 + 2097152;    // 1,048,576
    unsigned short* l16_3 = l16_2 + 1048576;    //   524,288
    unsigned short* qw16  = l16_3 + 524288;     //   196,608
    unsigned short* ow16  = qw16 + 196608;      //    65,536
    unsigned short* sw16  = ow16 + 65536;       //   131,072
    unsigned short* h16[4]  = {h16_0, h16_1, h16_2, h16_3};
    unsigned short* l16[4]  = {l16_0, l16_1, l16_2, l16_3};

    // ---- fused prep (guard + x16 + all weights) ----
    prep_kernel<<<(256 + 4194304 + 196608 + 65536 + 131072) / 256, 256, 0, stream>>>(
        x, qkv_w, out_w, stem_w, x16g, qw16, ow16, sw16);

    // ---- stem conv as bf16 GEMM (A staged directly from x16) ----
    stem_gemm_bf16<<<dim3(CH / 128, B_SZ * L_SEQ / 128), 256, 0, stream>>>(
        x16g, sw16, h16_0, stem_b);

    // ---- hierarchy levels ----
    for (int i = 0; i < NLEV; ++i) {
        const int l = L_SEQ >> i;
        const int M = B_SZ * l;
        gemm_bf16<<<dim3(768 / 128, M / 128), 256, 0, stream>>>(
            h16[i], qw16, qkv16, M, 768, CH);
        attn_mfma_kernel<<<M / 64, 256, 0, stream>>>(
            qkv16, h16[i], width_w, width_b, ov16, l);
        gemm_out_bf16<<<dim3(CH / 128, M / 128), 256, 0, stream>>>(
            ov16, ow16, (i == 0) ? lev0 : nullptr, l16[i],
            (i < NLEV - 1) ? h16[i + 1] : nullptr, M);
    }

    // ---- global attention + FiLM ----
    gattn_score_kernel<<<B_SZ * L_SEQ / 4, 256, 0, stream>>>(
        l16_0, l16_1, l16_2, l16_3, query, sbuf);
    softmax_L_kernel<<<B_SZ, 1024, 0, stream>>>(sbuf, pbuf);
    ctx_partial_kernel<<<dim3(64, B_SZ), 1024, 0, stream>>>(
        pbuf, l16_0, l16_1, l16_2, l16_3, partials);
    ctx_reduce_kernel<<<dim3(4, B_SZ), 256, 0, stream>>>(partials, ctx);
    film_kernel<<<128, 256, 0, stream>>>(ctx, film_w, film_b, film);
    final_kernel<<<(B_SZ * L_SEQ * CH) / 256, 256, 0, stream>>>(lev0, film, out);
}